// Round 14
// baseline (476.842 us; speedup 1.0000x reference)
//
#include <hip/hip_runtime.h>

// SelfAttention: out = softmax((xWq+bq)(xWk+bk)^T) @ Wout + bout
// B=8, N=2048, D=1024, fp32 in/out.
// Round 14: dephased-block split cores. 128x128 tiles, 4 waves, LDS 64KiB
// -> 2 independent blocks/CU whose barriers interleave, so one block's LDS
// reads/staging overlap the other's MFMA clusters (r11-r13 diagnosis: MFMA
// pipe at ~93% while busy, but busy only ~45% because the single block's
// waves are barrier-lockstepped). 16x16x32 3-MFMA split math (r9 numerics).
// S = x(WqWk^T)x^T; P@Wout 256x128 core unchanged.

typedef unsigned short u16;
typedef __bf16 bf16x8 __attribute__((ext_vector_type(8)));
typedef float f32x4 __attribute__((ext_vector_type(4)));

#define BB 8
#define NN 2048
#define DD 1024
#define MT (BB * NN)
#define PSTRIDE 4096  // u16 elems per P row (in-place over fp32 S rows)

#define MFMA3(d, ah, al, bh, bl)                                         \
  d = __builtin_amdgcn_mfma_f32_16x16x32_bf16(ah, bh, d, 0, 0, 0);       \
  d = __builtin_amdgcn_mfma_f32_16x16x32_bf16(ah, bl, d, 0, 0, 0);       \
  d = __builtin_amdgcn_mfma_f32_16x16x32_bf16(al, bh, d, 0, 0, 0);

static __device__ __forceinline__ u16 f2bf(float f) {
  unsigned u = __builtin_bit_cast(unsigned, f);
  u += 0x7FFFu + ((u >> 16) & 1u);
  return (u16)(u >> 16);
}
static __device__ __forceinline__ float bf2f(u16 h) {
  unsigned u = ((unsigned)h) << 16;
  return __builtin_bit_cast(float, u);
}

static __device__ __forceinline__ void gload16(const void* g, void* l) {
  __builtin_amdgcn_global_load_lds((const __attribute__((address_space(1))) void*)g,
                                   (__attribute__((address_space(3))) void*)l, 16, 0, 0);
}

// bijective XCD swizzle over a 1-D grid (gridDim.x % 8 == 0 for all callers)
static __device__ __forceinline__ int swz_wg() {
  int nwg = gridDim.x;
  int orig = blockIdx.x;
  int q = nwg >> 3;
  return (orig & 7) * q + (orig >> 3);
}

// ---------------- shared LDS swizzle helpers ------------------------------
// XOR-swizzle (T2): 16B chunk c of row r stored at c ^ ((r ^ r>>2) & 3).
#define SW(r) (((r) ^ ((r) >> 2)) & 3)

// stage a [128][32]-u16 plane with 256 threads (2 gloads/thread)
static __device__ __forceinline__ void stage_p128(const u16* __restrict__ g0,
                                                  u16* lp0, int tid, int ld) {
#pragma unroll
  for (int j = 0; j < 2; j++) {
    int o = tid + j * 256;  // 16B-chunk index 0..511 within plane
    int row = o >> 2, c = o & 3;
    const u16* g = g0 + (size_t)row * ld + ((c ^ SW(row)) << 3);  // inverse-swz src
    u16* lp = lp0 + (((tid >> 6) << 6) + j * 256) * 8;  // wave-uniform; HW adds lane*16B
    gload16(g, lp);
  }
}

// stage a [256][32]-u16 plane with 512 threads (2 gloads/thread)
static __device__ __forceinline__ void stage_plane_sw(const u16* __restrict__ g0,
                                                      u16* lp0, int tid, int ld) {
#pragma unroll
  for (int j = 0; j < 2; j++) {
    int o = tid + j * 512;
    int row = o >> 2, c = o & 3;
    const u16* g = g0 + (size_t)row * ld + ((c ^ SW(row)) << 3);
    u16* lp = lp0 + (((tid >> 6) << 6) + j * 512) * 8;
    gload16(g, lp);
  }
}

// stage a [128][32]-u16 plane with 512 threads (1 gload/thread)
static __device__ __forceinline__ void stage_half_sw(const u16* __restrict__ g0,
                                                     u16* lp0, int tid, int ld) {
  int o = tid;
  int row = o >> 2, c = o & 3;
  const u16* g = g0 + (size_t)row * ld + ((c ^ SW(row)) << 3);
  u16* lp = lp0 + ((tid >> 6) << 6) * 8;
  gload16(g, lp);
}

static __device__ __forceinline__ bf16x8 rdfrag(const u16* plane, int row, int g4) {
  return *(const bf16x8*)&plane[row * 32 + ((g4 ^ SW(row)) << 3)];
}

// ---------------- 128x128 dephased split-GEMM core ------------------------
// A,B: split bf16 planes, row-major [rows][1024]. Block = 256 threads =
// 4 waves (2m x 2n), per-wave out 64x64 = acc[4][4]. K = 1024, BK = 32.
// LDS: 2 bufs x 4 planes x [128][32] u16 = 64 KiB -> 2 blocks/CU (dephased).
// Per tile: ph0 {read A(8)+B01(4); drain; MFMA fm0-3 x fn01},
//           ph1 {read B23(4); drain; MFMA fm0-3 x fn23; barrier -> planes free},
//           ph2 {stage 4 next planes; vmcnt(8); barrier -> next buf ready}.
template <bool STG, int VM>
static __device__ __forceinline__ void tile128(
    u16* Lc, const u16* Ah, const u16* Al, const u16* Bh, const u16* Bl, int kst,
    f32x4 (&acc)[4][4], int tid, int wr, int wc, int r16, int g4) {
  u16* PA0 = Lc;
  u16* PA1 = Lc + 4096;
  u16* PB0 = Lc + 8192;
  u16* PB1 = Lc + 12288;
  bf16x8 a0[4], a1[4], b0[4], b1[4];

  // ---- phase 0: read A fm0-3 (8) + B fn01 (4); drain; MFMA (8 chains)
#pragma unroll
  for (int fm = 0; fm < 4; fm++) {
    int rw = wr * 64 + fm * 16 + r16;
    a0[fm] = rdfrag(PA0, rw, g4);
    a1[fm] = rdfrag(PA1, rw, g4);
  }
#pragma unroll
  for (int fn = 0; fn < 2; fn++) {
    int rw = wc * 64 + fn * 16 + r16;
    b0[fn] = rdfrag(PB0, rw, g4);
    b1[fn] = rdfrag(PB1, rw, g4);
  }
  asm volatile("s_waitcnt lgkmcnt(0)" ::: "memory");
  __builtin_amdgcn_s_setprio(1);
#pragma unroll
  for (int fm = 0; fm < 4; fm++)
#pragma unroll
    for (int fn = 0; fn < 2; fn++) { MFMA3(acc[fm][fn], a0[fm], a1[fm], b0[fn], b1[fn]); }
  __builtin_amdgcn_s_setprio(0);

  // ---- phase 1: read B fn23 (4); drain; MFMA; barrier -> planes free
#pragma unroll
  for (int fn = 2; fn < 4; fn++) {
    int rw = wc * 64 + fn * 16 + r16;
    b0[fn] = rdfrag(PB0, rw, g4);
    b1[fn] = rdfrag(PB1, rw, g4);
  }
  asm volatile("s_waitcnt lgkmcnt(0)" ::: "memory");
  __builtin_amdgcn_s_setprio(1);
#pragma unroll
  for (int fm = 0; fm < 4; fm++)
#pragma unroll
    for (int fn = 2; fn < 4; fn++) { MFMA3(acc[fm][fn], a0[fm], a1[fm], b0[fn], b1[fn]); }
  __builtin_amdgcn_s_setprio(0);
  __builtin_amdgcn_s_barrier();  // all waves' A+B reads drained -> planes free

  // ---- phase 2: stage next tile's 4 planes; counted vmcnt; barrier
  if (STG) {
    stage_p128(Ah + kst, PA0, tid, DD);
    stage_p128(Al + kst, PA1, tid, DD);
    stage_p128(Bh + kst, PB0, tid, DD);
    stage_p128(Bl + kst, PB1, tid, DD);
  }
  if (VM == 8) {
    asm volatile("s_waitcnt vmcnt(8)" ::: "memory");
  } else if (VM == 0) {
    asm volatile("s_waitcnt vmcnt(0)" ::: "memory");
  }
  __builtin_amdgcn_s_barrier();  // next tile's buffer fully landed for all
}

static __device__ __forceinline__ void mm4_core(u16* L, const u16* Ah, const u16* Al,
                                                const u16* Bh, const u16* Bl,
                                                f32x4 (&acc)[4][4], int tid) {
  int lane = tid & 63, r16 = lane & 15, g4 = lane >> 4;
  int w = tid >> 6, wr = w >> 1, wc = w & 1;
  u16* L0 = L;
  u16* L1 = L + 16384;
  // prologue: tile0 -> buf0, tile1 -> buf1 (8 gloads/thread each)
  stage_p128(Ah + 0, L0 + 0, tid, DD);
  stage_p128(Al + 0, L0 + 4096, tid, DD);
  stage_p128(Bh + 0, L0 + 8192, tid, DD);
  stage_p128(Bl + 0, L0 + 12288, tid, DD);
  stage_p128(Ah + 32, L1 + 0, tid, DD);
  stage_p128(Al + 32, L1 + 4096, tid, DD);
  stage_p128(Bh + 32, L1 + 8192, tid, DD);
  stage_p128(Bl + 32, L1 + 12288, tid, DD);
  asm volatile("s_waitcnt vmcnt(8)" ::: "memory");
  __builtin_amdgcn_s_barrier();
#pragma unroll 1
  for (int i = 0; i < 15; i++) {
    int t0 = 2 * i;
    tile128<true, 8>(L0, Ah, Al, Bh, Bl, (t0 + 2) * 32, acc, tid, wr, wc, r16, g4);
    tile128<true, 8>(L1, Ah, Al, Bh, Bl, (t0 + 3) * 32, acc, tid, wr, wc, r16, g4);
  }
  tile128<false, 0>(L0, Ah, Al, Bh, Bl, 0, acc, tid, wr, wc, r16, g4);   // t=30
  tile128<false, -1>(L1, Ah, Al, Bh, Bl, 0, acc, tid, wr, wc, r16, g4);  // t=31
}

// ---- S[b] = y[b] @ x[b]^T (fp32 out). grid = nb*256 blocks of 256 --------
__launch_bounds__(256, 2)
__global__ void k_gemm_s8(const u16* __restrict__ yh, const u16* __restrict__ yl,
                          const u16* __restrict__ xh, const u16* __restrict__ xl,
                          float* __restrict__ S) {
  __shared__ __attribute__((aligned(16))) u16 lds[2][4][4096];
  int wg = swz_wg();
  int nt = wg & 15, mtot = wg >> 4;
  int b = mtot >> 4, mt = mtot & 15;
  const size_t po = (size_t)b * NN * DD;
  const u16* Ah = yh + po + (size_t)(mt * 128) * DD;
  const u16* Al = yl + po + (size_t)(mt * 128) * DD;
  const u16* Bh = xh + po + (size_t)(nt * 128) * DD;
  const u16* Bl = xl + po + (size_t)(nt * 128) * DD;
  int tid = threadIdx.x;
  f32x4 acc[4][4] = {};
  mm4_core(&lds[0][0][0], Ah, Al, Bh, Bl, acc, tid);
  int lane = tid & 63, r16 = lane & 15, g4 = lane >> 4;
  int w = tid >> 6, wr = w >> 1, wc = w & 1;
  float* Sb = S + (size_t)b * NN * NN;
#pragma unroll
  for (int fm = 0; fm < 4; fm++)
#pragma unroll
    for (int fn = 0; fn < 4; fn++) {
      int col = nt * 128 + wc * 64 + fn * 16 + r16;
      int row = mt * 128 + wr * 64 + fm * 16 + g4 * 4;
#pragma unroll
      for (int i2 = 0; i2 < 4; i2++)
        Sb[(size_t)(row + i2) * NN + col] = acc[fm][fn][i2];
    }
}

// ---- C = A @ B^T with split bf16 planes out (y GEMM) ---------------------
// grid = (M/128)*8 blocks of 256 (Nout = 1024 -> 8 col tiles).
__launch_bounds__(256, 2)
__global__ void k_gemm_y8(const u16* __restrict__ ah_g, const u16* __restrict__ al_g,
                          const u16* __restrict__ bh_g, const u16* __restrict__ bl_g,
                          u16* __restrict__ ohi, u16* __restrict__ olo) {
  __shared__ __attribute__((aligned(16))) u16 lds[2][4][4096];
  int wg = swz_wg();
  int nt = wg & 7, mt = wg >> 3;
  const u16* Ah = ah_g + (size_t)(mt * 128) * DD;
  const u16* Al = al_g + (size_t)(mt * 128) * DD;
  const u16* Bh = bh_g + (size_t)(nt * 128) * DD;
  const u16* Bl = bl_g + (size_t)(nt * 128) * DD;
  int tid = threadIdx.x;
  f32x4 acc[4][4] = {};
  mm4_core(&lds[0][0][0], Ah, Al, Bh, Bl, acc, tid);
  int lane = tid & 63, r16 = lane & 15, g4 = lane >> 4;
  int w = tid >> 6, wr = w >> 1, wc = w & 1;
#pragma unroll
  for (int fm = 0; fm < 4; fm++)
#pragma unroll
    for (int fn = 0; fn < 4; fn++) {
      int col = nt * 128 + wc * 64 + fn * 16 + r16;
      int row = mt * 128 + wr * 64 + fm * 16 + g4 * 4;
#pragma unroll
      for (int i2 = 0; i2 < 4; i2++) {
        float v = acc[fm][fn][i2];
        u16 h = f2bf(v);
        size_t o = (size_t)(row + i2) * DD + col;
        ohi[o] = h;
        olo[o] = f2bf(v - bf2f(h));
      }
    }
}

// ---------------- Mt prep: K-sliced 128^2 split GEMM (unchanged) ----------
static __device__ __forceinline__ void stage128_lin(const u16* __restrict__ g0,
                                                    u16* lp0, int tid, int ld) {
#pragma unroll
  for (int j = 0; j < 2; j++) {
    int o = tid + j * 256;  // chunk 0..511
    const u16* g = g0 + (size_t)(o >> 2) * ld + (o & 3) * 8;
    u16* lp = lp0 + (((tid >> 6) << 6) + j * 256) * 8;
    gload16(g, lp);
  }
}

__launch_bounds__(256)
__global__ void k_gemm_mt(const u16* __restrict__ wkh, const u16* __restrict__ wkl,
                          const u16* __restrict__ wqh, const u16* __restrict__ wql,
                          float* __restrict__ part) {
  __shared__ __attribute__((aligned(16))) u16 lds[4][128][32];
  int idx = blockIdx.x;
  int ks = idx >> 6, mt = (idx >> 3) & 7, nt = idx & 7;
  int t = threadIdx.x, lane = t & 63, w = t >> 6;
  int wr = w >> 1, wc = w & 1, r16 = lane & 15, g = lane >> 4;
  const u16* Ah = wkh + (size_t)(mt * 128) * DD;
  const u16* Al = wkl + (size_t)(mt * 128) * DD;
  const u16* Bh = wqh + (size_t)(nt * 128) * DD;
  const u16* Bl = wql + (size_t)(nt * 128) * DD;
  float* P = part + (size_t)ks * DD * DD;

  f32x4 acc[4][4] = {};
  for (int k0 = ks * 256; k0 < ks * 256 + 256; k0 += 32) {
    stage128_lin(Ah + k0, &lds[0][0][0], t, DD);
    stage128_lin(Al + k0, &lds[1][0][0], t, DD);
    stage128_lin(Bh + k0, &lds[2][0][0], t, DD);
    stage128_lin(Bl + k0, &lds[3][0][0], t, DD);
    asm volatile("s_waitcnt vmcnt(0)" ::: "memory");
    __syncthreads();
    bf16x8 bh[4], bl[4];
#pragma unroll
    for (int fn = 0; fn < 4; fn++) {
      int col = wc * 64 + fn * 16 + r16;
      bh[fn] = *(const bf16x8*)&lds[2][col][g * 8];
      bl[fn] = *(const bf16x8*)&lds[3][col][g * 8];
    }
#pragma unroll
    for (int fm = 0; fm < 4; fm++) {
      int row = wr * 64 + fm * 16 + r16;
      bf16x8 ah = *(const bf16x8*)&lds[0][row][g * 8];
      bf16x8 al = *(const bf16x8*)&lds[1][row][g * 8];
#pragma unroll
      for (int fn = 0; fn < 4; fn++) { MFMA3(acc[fm][fn], ah, al, bh[fn], bl[fn]); }
    }
    __syncthreads();
  }
#pragma unroll
  for (int fm = 0; fm < 4; fm++)
#pragma unroll
    for (int fn = 0; fn < 4; fn++) {
      int col = nt * 128 + wc * 64 + fn * 16 + r16;
      int row = mt * 128 + wr * 64 + fm * 16 + g * 4;
#pragma unroll
      for (int i = 0; i < 4; i++)
        P[(size_t)(row + i) * DD + col] = acc[fm][fn][i];
    }
}

// combine 4 partial slices + split to hi/lo bf16 planes
__global__ void k_combine_split(const float* __restrict__ part, u16* __restrict__ hi,
                                u16* __restrict__ lo) {
  const long n4 = (long)DD * DD / 4;
  long i = (long)blockIdx.x * blockDim.x + threadIdx.x;
  long stride = (long)gridDim.x * blockDim.x;
  const float4* p0 = (const float4*)part;
  const float4* p1 = (const float4*)(part + (size_t)DD * DD);
  const float4* p2 = (const float4*)(part + (size_t)2 * DD * DD);
  const float4* p3 = (const float4*)(part + (size_t)3 * DD * DD);
  for (; i < n4; i += stride) {
    float4 a = p0[i], b = p1[i], c = p2[i], d = p3[i];
    float4 v;
    v.x = a.x + b.x + c.x + d.x;
    v.y = a.y + b.y + c.y + d.y;
    v.z = a.z + b.z + c.z + d.z;
    v.w = a.w + b.w + c.w + d.w;
    u16 h0 = f2bf(v.x), h1 = f2bf(v.y), h2 = f2bf(v.z), h3 = f2bf(v.w);
    ushort4 hv; hv.x = h0; hv.y = h1; hv.z = h2; hv.w = h3;
    ushort4 lv;
    lv.x = f2bf(v.x - bf2f(h0)); lv.y = f2bf(v.y - bf2f(h1));
    lv.z = f2bf(v.z - bf2f(h2)); lv.w = f2bf(v.w - bf2f(h3));
    ((ushort4*)hi)[i] = hv;
    ((ushort4*)lo)[i] = lv;
  }
}

// ---------------- 256x128 pipelined PLAIN-bf16 out core (r9) --------------
template <bool STG, int VM>
static __device__ __forceinline__ void tile4q(
    u16* Lc, const u16* Ag, const u16* Bg, int kst,
    f32x4 (&acc)[4][4], int tid, int wm, int wn, int r16, int g4) {
  u16* PA = Lc;          // [256][32]
  u16* PB = Lc + 8192;   // [128][32]
  bf16x8 a4[4], b4[4];

  // ph0: read A fm01 + B fn01; MFMA 2x2
#pragma unroll
  for (int fm = 0; fm < 2; fm++) a4[fm] = rdfrag(PA, wm * 64 + fm * 16 + r16, g4);
#pragma unroll
  for (int fn = 0; fn < 2; fn++) b4[fn] = rdfrag(PB, wn * 64 + fn * 16 + r16, g4);
  asm volatile("s_waitcnt lgkmcnt(0)" ::: "memory");
  __builtin_amdgcn_s_setprio(1);
#pragma unroll
  for (int fm = 0; fm < 2; fm++)
#pragma unroll
    for (int fn = 0; fn < 2; fn++)
      acc[fm][fn] = __builtin_amdgcn_mfma_f32_16x16x32_bf16(a4[fm], b4[fn], acc[fm][fn], 0, 0, 0);
  __builtin_amdgcn_s_setprio(0);

  // ph1: read B fn23; MFMA fm01 x fn23; barrier -> B plane free
#pragma unroll
  for (int fn = 2; fn < 4; fn++) b4[fn] = rdfrag(PB, wn * 64 + fn * 16 + r16, g4);
  asm volatile("s_waitcnt lgkmcnt(0)" ::: "memory");
  __builtin_amdgcn_s_setprio(1);
#pragma unroll
  for (int fm = 0; fm < 2; fm++)
#pragma unroll
    for (int fn = 2; fn < 4; fn++)
      acc[fm][fn] = __builtin_amdgcn_mfma_f32_16x16x32_bf16(a4[fm], b4[fn], acc[fm][fn], 0, 0, 0);
  __builtin_amdgcn_s_setprio(0);
  __builtin_amdgcn_s_barrier();  // B reads drained -> B plane free

  // ph2: read A fm23; stage next B; MFMA fm23 x fn01; barrier -> A free
#pragma unroll
  for (int fm = 2; fm < 4; fm++) a4[fm] = rdfrag(PA, wm * 64 + fm * 16 + r16, g4);
  if (STG) stage_half_sw(Bg + kst, PB, tid, NN);
  asm volatile("s_waitcnt lgkmcnt(0)" ::: "memory");
  __builtin_amdgcn_s_setprio(1);
#pragma unroll
  for (int fm = 2; fm < 4; fm++)
#pragma unroll
    for (int fn = 0; fn < 2; fn++)
      acc[fm][fn] = __builtin_amdgcn_mfma_f32_16x16x32_bf16(a4[fm], b4[fn], acc[fm][fn], 0, 0, 0);
  __builtin_amdgcn_s_setprio(0);
  __builtin_amdgcn_s_barrier();  // A reads drained -> A plane free

  // ph3: stage next A; counted vmcnt; barrier; MFMA fm23 x fn23
  if (STG) stage_plane_sw(Ag + kst, PA, tid, PSTRIDE);
  if (VM == 3) {
    asm volatile("s_waitcnt vmcnt(3)" ::: "memory");
  } else if (VM == 0) {
    asm volatile("s_waitcnt vmcnt(0)" ::: "memory");
  }
  __builtin_amdgcn_s_barrier();
  __builtin_amdgcn_s_setprio(1);
#pragma unroll
  for (int fm = 2; fm < 4; fm++)
#pragma unroll
    for (int fn = 2; fn < 4; fn++)
      acc[fm][fn] = __builtin_amdgcn_mfma_f32_16x16x32_bf16(a4[fm], b4[fn], acc[fm][fn], 0, 0, 0);
  __builtin_amdgcn_s_setprio(0);
}

// ---- out[b] = P[b] @ Wout + bout. grid = nb*64 blocks of 512 -------------
__launch_bounds__(512, 2)
__global__ void k_gemm_out(const u16* __restrict__ P, const u16* __restrict__ woutT,
                           const float* __restrict__ bout, float* __restrict__ out) {
  __shared__ __attribute__((aligned(16))) u16 lds[2][12288];
  int wg = swz_wg();
  int b = wg >> 6, mt = (wg >> 3) & 7, nt = wg & 7;
  const u16* Ag = P + (size_t)b * NN * PSTRIDE + (size_t)(mt * 256) * PSTRIDE;
  const u16* Bg = woutT + (size_t)(nt * 128) * NN;
  float* ob = out + (size_t)b * NN * DD;

  int tid = threadIdx.x;
  int lane = tid & 63, r16 = lane & 15, g4 = lane >> 4;
  int w = tid >> 6, wm = w >> 1, wn = w & 1;
  u16* L0 = &lds[0][0];
  u16* L1 = &lds[1][0];

  f32x4 acc[4][4] = {};
  stage_plane_sw(Ag + 0, L0, tid, PSTRIDE);
  stage_half_sw(Bg + 0, L0 + 8192, tid, NN);
  stage_plane_sw(Ag + 32, L1, tid, PSTRIDE);
  stage_half_sw(Bg + 32, L1 + 8192, tid, NN);
  asm volatile("s_waitcnt vmcnt(3)" ::: "memory");
  __builtin_amdgcn_s_barrier();
#pragma unroll 1
  for (int i = 0; i < 31; i++) {  // K = 2048 -> 64 tiles
    int t0 = 2 * i;
    tile4q<true, 3>(L0, Ag, Bg, (t0 + 2) * 32, acc, tid, wm, wn, r16, g4);
    tile4q<true, 3>(L1, Ag, Bg, (t0 + 3) * 32, acc, tid, wm, wn, r16, g4);
  }
  tile4q<false, 0>(L0, Ag, Bg, 0, acc, tid, wm, wn, r16, g4);   // t=62
  tile4q<false, -1>(L1, Ag, Bg, 0, acc, tid, wm, wn, r16, g4);  // t=63

#pragma unroll
  for (int fm = 0; fm < 4; fm++)
#pragma unroll
    for (int fn = 0; fn < 4; fn++) {
      int col = nt * 128 + wn * 64 + fn * 16 + r16;  // d in [0,1024)
      float bv = bout[col];
      int row = mt * 256 + wm * 64 + fm * 16 + g4 * 4;
#pragma unroll
      for (int i2 = 0; i2 < 4; i2++)
        ob[(size_t)(row + i2) * DD + col] = acc[fm][fn][i2] + bv;
    }
}

// ---- prep: split fp32 -> hi/lo bf16 planes (weights) ---------------------
__global__ void k_split(const float* __restrict__ x, u16* __restrict__ hi,
                        u16* __restrict__ lo, long n4) {
  long i = (long)blockIdx.x * blockDim.x + threadIdx.x;
  long stride = (long)gridDim.x * blockDim.x;
  for (; i < n4; i += stride) {
    float4 v = ((const float4*)x)[i];
    u16 h0 = f2bf(v.x), h1 = f2bf(v.y), h2 = f2bf(v.z), h3 = f2bf(v.w);
    ushort4 hv; hv.x = h0; hv.y = h1; hv.z = h2; hv.w = h3;
    ushort4 lv;
    lv.x = f2bf(v.x - bf2f(h0)); lv.y = f2bf(v.y - bf2f(h1));
    lv.z = f2bf(v.z - bf2f(h2)); lv.w = f2bf(v.w - bf2f(h3));
    ((ushort4*)hi)[i] = hv;
    ((ushort4*)lo)[i] = lv;
  }
}

// ---- fused: split x rows into hi/lo planes AND c2[row] = x[row,:].v2 -----
__global__ void k_split_x(const float* __restrict__ x, const float* __restrict__ v2,
                          u16* __restrict__ hi, u16* __restrict__ lo,
                          float* __restrict__ c2) {
  int w = threadIdx.x >> 6, lane = threadIdx.x & 63;
  int row = blockIdx.x * 4 + w;
  const float4* xr = (const float4*)(x + (size_t)row * DD);
  const float4* vv = (const float4*)v2;
  ushort4* hr = (ushort4*)(hi + (size_t)row * DD);
  ushort4* lr = (ushort4*)(lo + (size_t)row * DD);
  float s = 0.f;
#pragma unroll
  for (int j = 0; j < 4; j++) {
    int idx = j * 64 + lane;
    float4 v = xr[idx];
    float4 b = vv[idx];
    s += v.x * b.x + v.y * b.y + v.z * b.z + v.w * b.w;
    u16 h0 = f2bf(v.x), h1 = f2bf(v.y), h2 = f2bf(v.z), h3 = f2bf(v.w);
    ushort4 hv; hv.x = h0; hv.y = h1; hv.z = h2; hv.w = h3;
    ushort4 lv;
    lv.x = f2bf(v.x - bf2f(h0)); lv.y = f2bf(v.y - bf2f(h1));
    lv.z = f2bf(v.z - bf2f(h2)); lv.w = f2bf(v.w - bf2f(h3));
    hr[idx] = hv;
    lr[idx] = lv;
  }
#pragma unroll
  for (int o = 32; o > 0; o >>= 1) s += __shfl_xor(s, o);
  if (lane == 0) c2[row] = s;
}

// ---- prep: transpose RxC fp32 -> CxR bf16 (hi only) ----------------------
__global__ void k_transpose_split(const float* __restrict__ W, u16* __restrict__ thi,
                                  int R, int C) {
  __shared__ float tile[32][33];
  int c0 = blockIdx.x * 32, r0 = blockIdx.y * 32;
  int tx = threadIdx.x, ty = threadIdx.y;  // block (32,8)
#pragma unroll
  for (int i = 0; i < 4; i++)
    tile[ty + i * 8][tx] = W[(size_t)(r0 + ty + i * 8) * C + c0 + tx];
  __syncthreads();
#pragma unroll
  for (int i = 0; i < 4; i++) {
    float v = tile[tx][ty + i * 8];
    thi[(size_t)(c0 + ty + i * 8) * R + r0 + tx] = f2bf(v);
  }
}

// ---- matvec: out[r] = A[r,:] . v  (wave per row) -------------------------
__global__ void k_matvec(const float* __restrict__ A, const float* __restrict__ v,
                         float* __restrict__ out, int cols) {
  int w = threadIdx.x >> 6, lane = threadIdx.x & 63;
  int row = blockIdx.x * 4 + w;
  const float4* Ar = (const float4*)(A + (size_t)row * cols);
  const float4* vv = (const float4*)v;
  float s = 0.f;
  for (int j = lane; j < cols / 4; j += 64) {
    float4 a = Ar[j], b = vv[j];
    s += a.x * b.x + a.y * b.y + a.z * b.z + a.w * b.w;
  }
#pragma unroll
  for (int o = 32; o > 0; o >>= 1) s += __shfl_xor(s, o);
  if (lane == 0) out[row] = s;
}

// ---- softmax rows of S (+ per-col bias c2) -> P bf16 IN PLACE ------------
__global__ void k_softmax(float* __restrict__ S, const float* __restrict__ c2, int nrows) {
  int w = threadIdx.x >> 6, lane = threadIdx.x & 63;
  int row = blockIdx.x * 4 + w;
  if (row >= nrows) return;
  const float4* Sr = (const float4*)(S + (size_t)row * NN);
  const float4* c2b = (const float4*)(c2 + ((size_t)(row >> 11) << 11));
  float4 v[8];
  float mx = -3.4e38f;
#pragma unroll
  for (int j = 0; j < 8; j++) {
    v[j] = Sr[j * 64 + lane];
    float4 c = c2b[j * 64 + lane];
    v[j].x += c.x; v[j].y += c.y; v[j].z += c.z; v[j].w += c.w;
    mx = fmaxf(mx, fmaxf(fmaxf(v[j].x, v[j].y), fmaxf(v[j].z, v[j].w)));
  }
#pragma unroll
  for (int o = 32; o > 0; o >>= 1) mx = fmaxf(mx, __shfl_xor(mx, o));
  float e[32];
  float sum = 0.f;
#pragma unroll
  for (int j = 0; j < 8; j++) {
    e[j * 4 + 0] = __expf(v[j].x - mx);
    e[j * 4 + 1] = __expf(v[j].y - mx);
    e[j * 4 + 2] = __expf(v[j].z - mx);
    e[j * 4 + 3] = __expf(v[j].w - mx);
    sum += e[j * 4 + 0] + e[j * 4 + 1] + e[j * 4 + 2] + e[j * 4 + 3];
  }
#pragma unroll
  for (int o = 32; o > 0; o >>= 1) sum += __shfl_xor(sum, o);
  float inv = 1.0f / sum;  // depends on every lane's loads -> safe to overwrite row
  ushort4* Pr = (ushort4*)((u16*)S + (size_t)row * PSTRIDE);
#pragma unroll
  for (int j = 0; j < 8; j++) {
    ushort4 pv;
    pv.x = f2bf(e[j * 4 + 0] * inv);
    pv.y = f2bf(e[j * 4 + 1] * inv);
    pv.z = f2bf(e[j * 4 + 2] * inv);
    pv.w = f2bf(e[j * 4 + 3] * inv);
    Pr[j * 64 + lane] = pv;
  }
}

extern "C" void kernel_launch(void* const* d_in, const int* in_sizes, int n_in,
                              void* d_out, int out_size, void* d_ws, size_t ws_size,
                              hipStream_t stream) {
  const float* x = (const float*)d_in[0];
  const float* Wq = (const float*)d_in[1];
  const float* bq = (const float*)d_in[2];
  const float* Wk = (const float*)d_in[3];
  const float* bk = (const float*)d_in[4];
  const float* Wout = (const float*)d_in[5];
  const float* bout = (const float*)d_in[6];
  float* out = (float*)d_out;
  char* ws = (char*)d_ws;

  const size_t MB = 1ull << 20;
  u16* mth = (u16*)(ws + 0 * MB);
  u16* mtl = (u16*)(ws + 2 * MB);
  u16* woutT = (u16*)(ws + 4 * MB);            // 4 MiB [1024][2048]
  float* v2 = (float*)(ws + 8 * MB);           // 4 KiB
  float* c2 = (float*)(ws + 8 * MB + 65536);   // 64 KiB
  char* base = ws + 12 * MB;

  dim3 tb(32, 8, 1);

  if (ws_size >= 204 * MB) {
    // Tier A: xh/xl [0,64), yh/yl [64,128), S/scratch [128,192)
    u16* xh = (u16*)(base);
    u16* xl = (u16*)(base + 32 * MB);
    u16* yh = (u16*)(base + 64 * MB);
    u16* yl = (u16*)(base + 96 * MB);
    char* R = base + 128 * MB;  // 64 MiB scratch: W planes + Mt partials, then S
    u16* wqh = (u16*)(R);
    u16* wql = (u16*)(R + 2 * MB);
    u16* wkh = (u16*)(R + 4 * MB);
    u16* wkl = (u16*)(R + 6 * MB);
    float* mtp = (float*)(R + 8 * MB);  // 16 MiB partials
    float* S = (float*)R;

    // prep
    k_split<<<256, 256, 0, stream>>>(Wq, wqh, wql, (long)DD * DD / 4);
    k_split<<<256, 256, 0, stream>>>(Wk, wkh, wkl, (long)DD * DD / 4);
    k_gemm_mt<<<256, 256, 0, stream>>>(wkh, wkl, wqh, wql, mtp);
    k_combine_split<<<256, 256, 0, stream>>>(mtp, mth, mtl);
    k_transpose_split<<<dim3(32, 64, 1), tb, 0, stream>>>(Wout, woutT, 2048, 1024);
    k_matvec<<<256, 256, 0, stream>>>(Wk, bq, v2, DD);
    k_split_x<<<MT / 4, 256, 0, stream>>>(x, v2, xh, xl, c2);
    // y = x @ Mt^T
    k_gemm_y8<<<1024, 256, 0, stream>>>(xh, xl, mth, mtl, yh, yl);
    // per 4-batch half: S, softmax, out
    for (int h = 0; h < 2; h++) {
      size_t qo = (size_t)h * 4 * NN * DD;
      k_gemm_s8<<<1024, 256, 0, stream>>>(yh + qo, yl + qo, xh + qo, xl + qo, S);
      k_softmax<<<4 * NN / 4, 256, 0, stream>>>(S, c2 + (size_t)h * 4 * NN, 4 * NN);
      k_gemm_out<<<256, 512, 0, stream>>>((const u16*)S, woutT, bout, out + qo);
    }
  } else if (ws_size >= 156 * MB) {
    // Tier B: xh/xl [0,64), yh/yl [64,128), S 16MB at [128,144)
    u16* xh = (u16*)(base);
    u16* xl = (u16*)(base + 32 * MB);
    u16* yh = (u16*)(base + 64 * MB);
    u16* yl = (u16*)(base + 96 * MB);
    char* R = base + 128 * MB;
    u16* wqh = (u16*)(R);
    u16* wql = (u16*)(R + 2 * MB);
    u16* wkh = (u16*)(R + 4 * MB);
    u16* wkl = (u16*)(R + 6 * MB);
    float* mtp = (float*)yh;  // 16 MiB partials in (not-yet-written) yh region
    float* S = (float*)R;

    k_split<<<256, 256, 0, stream>>>(Wq, wqh, wql, (long)DD * DD / 4);
    k_split<<<256, 256, 0, stream>>>(Wk, wkh, wkl, (long)DD * DD / 4);
    k_gemm_mt<<<256, 256, 0, stream>>>(wkh, wkl, wqh, wql, mtp);
    k_combine_split<<<256, 256, 0, stream>>>(mtp, mth, mtl);
    k_transpose_split<<<dim3(32, 64, 1), tb, 0, stream>>>(Wout, woutT, 2048, 1024);
    k_matvec<<<256, 256, 0, stream>>>(Wk, bq, v2, DD);
    k_split_x<<<MT / 4, 256, 0, stream>>>(x, v2, xh, xl, c2);
    k_gemm_y8<<<1024, 256, 0, stream>>>(xh, xl, mth, mtl, yh, yl);
    for (int b = 0; b < BB; b++) {
      size_t qo = (size_t)b * NN * DD;
      k_gemm_s8<<<256, 256, 0, stream>>>(yh + qo, yl + qo, xh + qo, xl + qo, S);
      k_softmax<<<NN / 4, 256, 0, stream>>>(S, c2 + (size_t)b * NN, NN);
      k_gemm_out<<<64, 512, 0, stream>>>((const u16*)S, woutT, bout, out + qo);
    }
  } else {
    // Tier C (60 MiB): per 2-batch chunk, xh/xl 16MB, yh/yl 16MB, S 16MB
    u16* xh = (u16*)(base);
    u16* xl = (u16*)(base + 8 * MB);
    u16* yh = (u16*)(base + 16 * MB);
    u16* yl = (u16*)(base + 24 * MB);
    char* R = base + 32 * MB;
    u16* wqh = (u16*)(R);
    u16* wql = (u16*)(R + 2 * MB);
    u16* wkh = (u16*)(R + 4 * MB);
    u16* wkl = (u16*)(R + 6 * MB);
    float* mtp = (float*)yh;  // 16 MiB partials in yh region (written later)
    float* S = (float*)R;

    k_split<<<256, 256, 0, stream>>>(Wq, wqh, wql, (long)DD * DD / 4);
    k_split<<<256, 256, 0, stream>>>(Wk, wkh, wkl, (long)DD * DD / 4);
    k_gemm_mt<<<256, 256, 0, stream>>>(wkh, wkl, wqh, wql, mtp);
    k_combine_split<<<256, 256, 0, stream>>>(mtp, mth, mtl);
    k_transpose_split<<<dim3(32, 64, 1), tb, 0, stream>>>(Wout, woutT, 2048, 1024);
    k_matvec<<<256, 256, 0, stream>>>(Wk, bq, v2, DD);
    for (int c = 0; c < 4; c++) {
      size_t xo = (size_t)c * 2 * NN * DD;
      k_split_x<<<2 * NN / 4, 256, 0, stream>>>(x + xo, v2, xh, xl, c2 + (size_t)c * 2 * NN);
      k_gemm_y8<<<256, 256, 0, stream>>>(xh, xl, mth, mtl, yh, yl);
      for (int bi = 0; bi < 2; bi++) {
        size_t lo = (size_t)bi * NN * DD;
        k_gemm_s8<<<256, 256, 0, stream>>>(yh + lo, yl + lo, xh + lo, xl + lo, S);
        k_softmax<<<NN / 4, 256, 0, stream>>>(S, c2 + (size_t)(c * 2 + bi) * NN, NN);
        k_gemm_out<<<64, 512, 0, stream>>>((const u16*)S, woutT, bout, out + xo + lo);
      }
    }
  }
}

// Round 15
// 449.078 us; speedup vs baseline: 1.0618x; 1.0618x over previous
//
#include <hip/hip_runtime.h>

// SelfAttention: out = softmax((xWq+bq)(xWk+bk)^T) @ Wout + bout
// B=8, N=2048, D=1024, fp32 in/out.
// Round 15: r9 base (best, 438.7us) with ONE change: k_gemm_y8 uses the
// 128^2 2-blocks/CU core WITH a hashed per-block clock-spin skew (0-4095cy)
// so co-resident blocks run anti-phase (r14 failed because identical blocks
// stay phase-locked: no offset -> no read/MFMA overlap). y8 and each s8
// dispatch do identical FLOPs -> this bench is a direct within-run A/B.
// S = x(WqWk^T)x^T; score chain bf16 hi/lo split (3 MFMAs); P@Wout bf16.

typedef unsigned short u16;
typedef __bf16 bf16x8 __attribute__((ext_vector_type(8)));
typedef float f32x4 __attribute__((ext_vector_type(4)));

#define BB 8
#define NN 2048
#define DD 1024
#define MT (BB * NN)
#define PSTRIDE 4096  // u16 elems per P row (in-place over fp32 S rows)

#define MFMA3(d, ah, al, bh, bl)                                         \
  d = __builtin_amdgcn_mfma_f32_16x16x32_bf16(ah, bh, d, 0, 0, 0);       \
  d = __builtin_amdgcn_mfma_f32_16x16x32_bf16(ah, bl, d, 0, 0, 0);       \
  d = __builtin_amdgcn_mfma_f32_16x16x32_bf16(al, bh, d, 0, 0, 0);

static __device__ __forceinline__ u16 f2bf(float f) {
  unsigned u = __builtin_bit_cast(unsigned, f);
  u += 0x7FFFu + ((u >> 16) & 1u);
  return (u16)(u >> 16);
}
static __device__ __forceinline__ float bf2f(u16 h) {
  unsigned u = ((unsigned)h) << 16;
  return __builtin_bit_cast(float, u);
}

static __device__ __forceinline__ void gload16(const void* g, void* l) {
  __builtin_amdgcn_global_load_lds((const __attribute__((address_space(1))) void*)g,
                                   (__attribute__((address_space(3))) void*)l, 16, 0, 0);
}

// bijective XCD swizzle over a 1-D grid (gridDim.x % 8 == 0 for all callers)
static __device__ __forceinline__ int swz_wg() {
  int nwg = gridDim.x;
  int orig = blockIdx.x;
  int q = nwg >> 3;
  return (orig & 7) * q + (orig >> 3);
}

// pseudo-random per-block phase skew: 0..4095 cycles. Co-resident blocks get
// an expected ~1.4K-cycle relative offset -> anti-phase LDS/MFMA overlap.
static __device__ __forceinline__ void skew_spin() {
  unsigned h = (unsigned)blockIdx.x * 2654435761u;
  long long cyc = (long long)((h >> 16) & 4095u);
  long long t0 = clock64();
  while (clock64() - t0 < cyc) {}
}

// ---------------- shared LDS swizzle helpers ------------------------------
// XOR-swizzle (T2): 16B chunk c of row r stored at c ^ ((r ^ r>>2) & 3).
#define SW(r) (((r) ^ ((r) >> 2)) & 3)

// stage a [256][32]-u16 plane, generic row stride ld (2 gloads/thread @512t)
static __device__ __forceinline__ void stage_plane_sw(const u16* __restrict__ g0,
                                                      u16* lp0, int tid, int ld) {
#pragma unroll
  for (int j = 0; j < 2; j++) {
    int o = tid + j * 512;  // 16B-chunk index 0..1023 within plane
    int row = o >> 2, c = o & 3;
    const u16* g = g0 + (size_t)row * ld + ((c ^ SW(row)) << 3);  // inverse-swz src
    u16* lp = lp0 + (((tid >> 6) << 6) + j * 512) * 8;  // wave-uniform; HW adds lane*16B
    gload16(g, lp);
  }
}

// stage a [128][32]-u16 plane with 512 threads (1 gload/thread)
static __device__ __forceinline__ void stage_half_sw(const u16* __restrict__ g0,
                                                     u16* lp0, int tid, int ld) {
  int o = tid;  // chunk 0..511
  int row = o >> 2, c = o & 3;
  const u16* g = g0 + (size_t)row * ld + ((c ^ SW(row)) << 3);
  u16* lp = lp0 + ((tid >> 6) << 6) * 8;
  gload16(g, lp);
}

// stage a [128][32]-u16 plane with 256 threads (2 gloads/thread)
static __device__ __forceinline__ void stage_p128(const u16* __restrict__ g0,
                                                  u16* lp0, int tid, int ld) {
#pragma unroll
  for (int j = 0; j < 2; j++) {
    int o = tid + j * 256;  // chunk 0..511
    int row = o >> 2, c = o & 3;
    const u16* g = g0 + (size_t)row * ld + ((c ^ SW(row)) << 3);
    u16* lp = lp0 + (((tid >> 6) << 6) + j * 256) * 8;
    gload16(g, lp);
  }
}

static __device__ __forceinline__ bf16x8 rdfrag(const u16* plane, int row, int g4) {
  return *(const bf16x8*)&plane[row * 32 + ((g4 ^ SW(row)) << 3)];
}

// ---------------- 256x256 pipelined split-GEMM core (r9, unchanged) -------
template <bool STG, int VM>
static __device__ __forceinline__ void tile4(
    u16* Lc, const u16* Ah, const u16* Al, const u16* Bh, const u16* Bl, int kst,
    f32x4 (&acc)[8][4], int tid, int wm, int wn, int r16, int g4) {
  u16* PA0 = Lc;
  u16* PA1 = Lc + 8192;
  u16* PB0 = Lc + 16384;
  u16* PB1 = Lc + 24576;
  bf16x8 a0[4], a1[4], b0[4], b1[4];

  // ---- phase 0: read A-half0 + B(n0-1); MFMA (m0, n0-1)
#pragma unroll
  for (int fm = 0; fm < 4; fm++) {
    int rw = wm * 128 + fm * 16 + r16;
    a0[fm] = rdfrag(PA0, rw, g4);
    a1[fm] = rdfrag(PA1, rw, g4);
  }
#pragma unroll
  for (int fn = 0; fn < 2; fn++) {
    int rw = wn * 64 + fn * 16 + r16;
    b0[fn] = rdfrag(PB0, rw, g4);
    b1[fn] = rdfrag(PB1, rw, g4);
  }
  __builtin_amdgcn_s_barrier();
  asm volatile("s_waitcnt lgkmcnt(0)" ::: "memory");
  __builtin_amdgcn_s_setprio(1);
#pragma unroll
  for (int fm = 0; fm < 4; fm++)
#pragma unroll
    for (int fn = 0; fn < 2; fn++) { MFMA3(acc[fm][fn], a0[fm], a1[fm], b0[fn], b1[fn]); }
  __builtin_amdgcn_s_setprio(0);

  // ---- phase 1: read B(n2-3); MFMA (m0, n2-3)
#pragma unroll
  for (int fn = 2; fn < 4; fn++) {
    int rw = wn * 64 + fn * 16 + r16;
    b0[fn] = rdfrag(PB0, rw, g4);
    b1[fn] = rdfrag(PB1, rw, g4);
  }
  __builtin_amdgcn_s_barrier();
  asm volatile("s_waitcnt lgkmcnt(0)" ::: "memory");
  __builtin_amdgcn_s_setprio(1);
#pragma unroll
  for (int fm = 0; fm < 4; fm++)
#pragma unroll
    for (int fn = 2; fn < 4; fn++) { MFMA3(acc[fm][fn], a0[fm], a1[fm], b0[fn], b1[fn]); }
  __builtin_amdgcn_s_setprio(0);
  __builtin_amdgcn_s_barrier();  // all waves' B reads drained -> B planes free

  // ---- phase 2: read A-half1; stage next B planes; MFMA (m1, n0-1)
#pragma unroll
  for (int fm = 0; fm < 4; fm++) {
    int rw = wm * 128 + 64 + fm * 16 + r16;
    a0[fm] = rdfrag(PA0, rw, g4);
    a1[fm] = rdfrag(PA1, rw, g4);
  }
  if (STG) {
    stage_plane_sw(Bh + kst, PB0, tid, DD);
    stage_plane_sw(Bl + kst, PB1, tid, DD);
  }
  __builtin_amdgcn_s_barrier();
  asm volatile("s_waitcnt lgkmcnt(0)" ::: "memory");
  __builtin_amdgcn_s_setprio(1);
#pragma unroll
  for (int fm = 0; fm < 4; fm++)
#pragma unroll
    for (int fn = 0; fn < 2; fn++) { MFMA3(acc[fm + 4][fn], a0[fm], a1[fm], b0[fn], b1[fn]); }
  __builtin_amdgcn_s_setprio(0);
  __builtin_amdgcn_s_barrier();  // all waves' A reads drained -> A planes free

  // ---- phase 3: stage next A planes; counted vmcnt; barrier; MFMA (m1, n2-3)
  if (STG) {
    stage_plane_sw(Ah + kst, PA0, tid, DD);
    stage_plane_sw(Al + kst, PA1, tid, DD);
  }
  if (VM == 8) {
    asm volatile("s_waitcnt vmcnt(8)" ::: "memory");
  } else if (VM == 0) {
    asm volatile("s_waitcnt vmcnt(0)" ::: "memory");
  }
  __builtin_amdgcn_s_barrier();  // next tile's buffer fully landed for all
  __builtin_amdgcn_s_setprio(1);
#pragma unroll
  for (int fm = 0; fm < 4; fm++)
#pragma unroll
    for (int fn = 2; fn < 4; fn++) { MFMA3(acc[fm + 4][fn], a0[fm], a1[fm], b0[fn], b1[fn]); }
  __builtin_amdgcn_s_setprio(0);
}

static __device__ __forceinline__ void mm8_core(u16* L, const u16* Ah, const u16* Al,
                                                const u16* Bh, const u16* Bl,
                                                f32x4 (&acc)[8][4], int tid) {
  int lane = tid & 63, r16 = lane & 15, g4 = lane >> 4;
  int w = tid >> 6, wm = w >> 2, wn = w & 3;
  u16* L0 = L;
  u16* L1 = L + 4 * 8192;
  stage_plane_sw(Ah + 0, L0 + 0, tid, DD);
  stage_plane_sw(Al + 0, L0 + 8192, tid, DD);
  stage_plane_sw(Bh + 0, L0 + 16384, tid, DD);
  stage_plane_sw(Bl + 0, L0 + 24576, tid, DD);
  stage_plane_sw(Ah + 32, L1 + 0, tid, DD);
  stage_plane_sw(Al + 32, L1 + 8192, tid, DD);
  stage_plane_sw(Bh + 32, L1 + 16384, tid, DD);
  stage_plane_sw(Bl + 32, L1 + 24576, tid, DD);
  asm volatile("s_waitcnt vmcnt(8)" ::: "memory");
  __builtin_amdgcn_s_barrier();
#pragma unroll 1
  for (int i = 0; i < 15; i++) {
    int t0 = 2 * i;
    tile4<true, 8>(L0, Ah, Al, Bh, Bl, (t0 + 2) * 32, acc, tid, wm, wn, r16, g4);
    tile4<true, 8>(L1, Ah, Al, Bh, Bl, (t0 + 3) * 32, acc, tid, wm, wn, r16, g4);
  }
  tile4<false, 0>(L0, Ah, Al, Bh, Bl, 0, acc, tid, wm, wn, r16, g4);   // t=30
  tile4<false, -1>(L1, Ah, Al, Bh, Bl, 0, acc, tid, wm, wn, r16, g4);  // t=31
}

// ---- S[b] = y[b] @ x[b]^T (fp32 out). grid = nb*64 blocks of 512 ---------
__launch_bounds__(512, 2)
__global__ void k_gemm_s8(const u16* __restrict__ yh, const u16* __restrict__ yl,
                          const u16* __restrict__ xh, const u16* __restrict__ xl,
                          float* __restrict__ S) {
  __shared__ __attribute__((aligned(16))) u16 lds[2][4][8192];
  int wg = swz_wg();
  int nt = wg & 7, mtot = wg >> 3;
  int b = mtot >> 3, mt = mtot & 7;
  const size_t po = (size_t)b * NN * DD;
  const u16* Ah = yh + po + (size_t)(mt * 256) * DD;
  const u16* Al = yl + po + (size_t)(mt * 256) * DD;
  const u16* Bh = xh + po + (size_t)(nt * 256) * DD;
  const u16* Bl = xl + po + (size_t)(nt * 256) * DD;
  int tid = threadIdx.x;
  f32x4 acc[8][4] = {};
  mm8_core(&lds[0][0][0], Ah, Al, Bh, Bl, acc, tid);
  int lane = tid & 63, r16 = lane & 15, g4 = lane >> 4;
  int w = tid >> 6, wm = w >> 2, wn = w & 3;
  float* Sb = S + (size_t)b * NN * NN;
#pragma unroll
  for (int fm = 0; fm < 8; fm++)
#pragma unroll
    for (int fn = 0; fn < 4; fn++) {
      int col = nt * 256 + wn * 64 + fn * 16 + r16;
      int row = mt * 256 + wm * 128 + fm * 16 + g4 * 4;
#pragma unroll
      for (int i2 = 0; i2 < 4; i2++)
        Sb[(size_t)(row + i2) * NN + col] = acc[fm][fn][i2];
    }
}

// ---------------- 128x128 skewed split-GEMM core (y GEMM A/B test) --------
// Block = 256 threads = 4 waves (2m x 2n), per-wave 64x64 = acc[4][4].
// LDS 64 KiB -> 2 blocks/CU; skew_spin() de-phases them so one block's LDS
// reads overlap the other's MFMA clusters.
template <bool STG, int VM>
static __device__ __forceinline__ void tile128(
    u16* Lc, const u16* Ah, const u16* Al, const u16* Bh, const u16* Bl, int kst,
    f32x4 (&acc)[4][4], int tid, int wr, int wc, int r16, int g4) {
  u16* PA0 = Lc;
  u16* PA1 = Lc + 4096;
  u16* PB0 = Lc + 8192;
  u16* PB1 = Lc + 12288;
  bf16x8 a0[4], a1[4], b0[4], b1[4];

  // ---- phase 0: read A fm0-3 (8) + B fn01 (4); drain; MFMA (8 chains)
#pragma unroll
  for (int fm = 0; fm < 4; fm++) {
    int rw = wr * 64 + fm * 16 + r16;
    a0[fm] = rdfrag(PA0, rw, g4);
    a1[fm] = rdfrag(PA1, rw, g4);
  }
#pragma unroll
  for (int fn = 0; fn < 2; fn++) {
    int rw = wc * 64 + fn * 16 + r16;
    b0[fn] = rdfrag(PB0, rw, g4);
    b1[fn] = rdfrag(PB1, rw, g4);
  }
  asm volatile("s_waitcnt lgkmcnt(0)" ::: "memory");
  __builtin_amdgcn_s_setprio(1);
#pragma unroll
  for (int fm = 0; fm < 4; fm++)
#pragma unroll
    for (int fn = 0; fn < 2; fn++) { MFMA3(acc[fm][fn], a0[fm], a1[fm], b0[fn], b1[fn]); }
  __builtin_amdgcn_s_setprio(0);

  // ---- phase 1: read B fn23 (4); drain; MFMA; barrier -> planes free
#pragma unroll
  for (int fn = 2; fn < 4; fn++) {
    int rw = wc * 64 + fn * 16 + r16;
    b0[fn] = rdfrag(PB0, rw, g4);
    b1[fn] = rdfrag(PB1, rw, g4);
  }
  asm volatile("s_waitcnt lgkmcnt(0)" ::: "memory");
  __builtin_amdgcn_s_setprio(1);
#pragma unroll
  for (int fm = 0; fm < 4; fm++)
#pragma unroll
    for (int fn = 2; fn < 4; fn++) { MFMA3(acc[fm][fn], a0[fm], a1[fm], b0[fn], b1[fn]); }
  __builtin_amdgcn_s_setprio(0);
  __builtin_amdgcn_s_barrier();  // all waves' A+B reads drained -> planes free

  // ---- phase 2: stage next tile's 4 planes; counted vmcnt; barrier
  if (STG) {
    stage_p128(Ah + kst, PA0, tid, DD);
    stage_p128(Al + kst, PA1, tid, DD);
    stage_p128(Bh + kst, PB0, tid, DD);
    stage_p128(Bl + kst, PB1, tid, DD);
  }
  if (VM == 8) {
    asm volatile("s_waitcnt vmcnt(8)" ::: "memory");
  } else if (VM == 0) {
    asm volatile("s_waitcnt vmcnt(0)" ::: "memory");
  }
  __builtin_amdgcn_s_barrier();  // next tile's buffer fully landed for all
}

static __device__ __forceinline__ void mm4_core(u16* L, const u16* Ah, const u16* Al,
                                                const u16* Bh, const u16* Bl,
                                                f32x4 (&acc)[4][4], int tid) {
  int lane = tid & 63, r16 = lane & 15, g4 = lane >> 4;
  int w = tid >> 6, wr = w >> 1, wc = w & 1;
  u16* L0 = L;
  u16* L1 = L + 16384;
  stage_p128(Ah + 0, L0 + 0, tid, DD);
  stage_p128(Al + 0, L0 + 4096, tid, DD);
  stage_p128(Bh + 0, L0 + 8192, tid, DD);
  stage_p128(Bl + 0, L0 + 12288, tid, DD);
  stage_p128(Ah + 32, L1 + 0, tid, DD);
  stage_p128(Al + 32, L1 + 4096, tid, DD);
  stage_p128(Bh + 32, L1 + 8192, tid, DD);
  stage_p128(Bl + 32, L1 + 12288, tid, DD);
  asm volatile("s_waitcnt vmcnt(8)" ::: "memory");
  __builtin_amdgcn_s_barrier();
#pragma unroll 1
  for (int i = 0; i < 15; i++) {
    int t0 = 2 * i;
    tile128<true, 8>(L0, Ah, Al, Bh, Bl, (t0 + 2) * 32, acc, tid, wr, wc, r16, g4);
    tile128<true, 8>(L1, Ah, Al, Bh, Bl, (t0 + 3) * 32, acc, tid, wr, wc, r16, g4);
  }
  tile128<false, 0>(L0, Ah, Al, Bh, Bl, 0, acc, tid, wr, wc, r16, g4);   // t=30
  tile128<false, -1>(L1, Ah, Al, Bh, Bl, 0, acc, tid, wr, wc, r16, g4);  // t=31
}

// ---- C = A @ B^T split planes out (y GEMM). grid = (M/128)*8 of 256 ------
__launch_bounds__(256, 2)
__global__ void k_gemm_y8(const u16* __restrict__ ah_g, const u16* __restrict__ al_g,
                          const u16* __restrict__ bh_g, const u16* __restrict__ bl_g,
                          u16* __restrict__ ohi, u16* __restrict__ olo) {
  __shared__ __attribute__((aligned(16))) u16 lds[2][4][4096];
  int wg = swz_wg();
  int nt = wg & 7, mt = wg >> 3;
  const u16* Ah = ah_g + (size_t)(mt * 128) * DD;
  const u16* Al = al_g + (size_t)(mt * 128) * DD;
  const u16* Bh = bh_g + (size_t)(nt * 128) * DD;
  const u16* Bl = bl_g + (size_t)(nt * 128) * DD;
  int tid = threadIdx.x;
  skew_spin();  // de-phase co-resident blocks
  f32x4 acc[4][4] = {};
  mm4_core(&lds[0][0][0], Ah, Al, Bh, Bl, acc, tid);
  int lane = tid & 63, r16 = lane & 15, g4 = lane >> 4;
  int w = tid >> 6, wr = w >> 1, wc = w & 1;
#pragma unroll
  for (int fm = 0; fm < 4; fm++)
#pragma unroll
    for (int fn = 0; fn < 4; fn++) {
      int col = nt * 128 + wc * 64 + fn * 16 + r16;
      int row = mt * 128 + wr * 64 + fm * 16 + g4 * 4;
#pragma unroll
      for (int i2 = 0; i2 < 4; i2++) {
        float v = acc[fm][fn][i2];
        u16 h = f2bf(v);
        size_t o = (size_t)(row + i2) * DD + col;
        ohi[o] = h;
        olo[o] = f2bf(v - bf2f(h));
      }
    }
}

// ---------------- Mt prep: K-sliced 128^2 split GEMM (unchanged) ----------
static __device__ __forceinline__ void stage128_lin(const u16* __restrict__ g0,
                                                    u16* lp0, int tid, int ld) {
#pragma unroll
  for (int j = 0; j < 2; j++) {
    int o = tid + j * 256;  // chunk 0..511
    const u16* g = g0 + (size_t)(o >> 2) * ld + (o & 3) * 8;
    u16* lp = lp0 + (((tid >> 6) << 6) + j * 256) * 8;
    gload16(g, lp);
  }
}

__launch_bounds__(256)
__global__ void k_gemm_mt(const u16* __restrict__ wkh, const u16* __restrict__ wkl,
                          const u16* __restrict__ wqh, const u16* __restrict__ wql,
                          float* __restrict__ part) {
  __shared__ __attribute__((aligned(16))) u16 lds[4][128][32];
  int idx = blockIdx.x;
  int ks = idx >> 6, mt = (idx >> 3) & 7, nt = idx & 7;
  int t = threadIdx.x, lane = t & 63, w = t >> 6;
  int wr = w >> 1, wc = w & 1, r16 = lane & 15, g = lane >> 4;
  const u16* Ah = wkh + (size_t)(mt * 128) * DD;
  const u16* Al = wkl + (size_t)(mt * 128) * DD;
  const u16* Bh = wqh + (size_t)(nt * 128) * DD;
  const u16* Bl = wql + (size_t)(nt * 128) * DD;
  float* P = part + (size_t)ks * DD * DD;

  f32x4 acc[4][4] = {};
  for (int k0 = ks * 256; k0 < ks * 256 + 256; k0 += 32) {
    stage128_lin(Ah + k0, &lds[0][0][0], t, DD);
    stage128_lin(Al + k0, &lds[1][0][0], t, DD);
    stage128_lin(Bh + k0, &lds[2][0][0], t, DD);
    stage128_lin(Bl + k0, &lds[3][0][0], t, DD);
    asm volatile("s_waitcnt vmcnt(0)" ::: "memory");
    __syncthreads();
    bf16x8 bh[4], bl[4];
#pragma unroll
    for (int fn = 0; fn < 4; fn++) {
      int col = wc * 64 + fn * 16 + r16;
      bh[fn] = *(const bf16x8*)&lds[2][col][g * 8];
      bl[fn] = *(const bf16x8*)&lds[3][col][g * 8];
    }
#pragma unroll
    for (int fm = 0; fm < 4; fm++) {
      int row = wr * 64 + fm * 16 + r16;
      bf16x8 ah = *(const bf16x8*)&lds[0][row][g * 8];
      bf16x8 al = *(const bf16x8*)&lds[1][row][g * 8];
#pragma unroll
      for (int fn = 0; fn < 4; fn++) { MFMA3(acc[fm][fn], ah, al, bh[fn], bl[fn]); }
    }
    __syncthreads();
  }
#pragma unroll
  for (int fm = 0; fm < 4; fm++)
#pragma unroll
    for (int fn = 0; fn < 4; fn++) {
      int col = nt * 128 + wc * 64 + fn * 16 + r16;
      int row = mt * 128 + wr * 64 + fm * 16 + g * 4;
#pragma unroll
      for (int i = 0; i < 4; i++)
        P[(size_t)(row + i) * DD + col] = acc[fm][fn][i];
    }
}

// combine 4 partial slices + split to hi/lo bf16 planes
__global__ void k_combine_split(const float* __restrict__ part, u16* __restrict__ hi,
                                u16* __restrict__ lo) {
  const long n4 = (long)DD * DD / 4;
  long i = (long)blockIdx.x * blockDim.x + threadIdx.x;
  long stride = (long)gridDim.x * blockDim.x;
  const float4* p0 = (const float4*)part;
  const float4* p1 = (const float4*)(part + (size_t)DD * DD);
  const float4* p2 = (const float4*)(part + (size_t)2 * DD * DD);
  const float4* p3 = (const float4*)(part + (size_t)3 * DD * DD);
  for (; i < n4; i += stride) {
    float4 a = p0[i], b = p1[i], c = p2[i], d = p3[i];
    float4 v;
    v.x = a.x + b.x + c.x + d.x;
    v.y = a.y + b.y + c.y + d.y;
    v.z = a.z + b.z + c.z + d.z;
    v.w = a.w + b.w + c.w + d.w;
    u16 h0 = f2bf(v.x), h1 = f2bf(v.y), h2 = f2bf(v.z), h3 = f2bf(v.w);
    ushort4 hv; hv.x = h0; hv.y = h1; hv.z = h2; hv.w = h3;
    ushort4 lv;
    lv.x = f2bf(v.x - bf2f(h0)); lv.y = f2bf(v.y - bf2f(h1));
    lv.z = f2bf(v.z - bf2f(h2)); lv.w = f2bf(v.w - bf2f(h3));
    ((ushort4*)hi)[i] = hv;
    ((ushort4*)lo)[i] = lv;
  }
}

// ---------------- 256x128 pipelined PLAIN-bf16 out core (r9) --------------
template <bool STG, int VM>
static __device__ __forceinline__ void tile4q(
    u16* Lc, const u16* Ag, const u16* Bg, int kst,
    f32x4 (&acc)[4][4], int tid, int wm, int wn, int r16, int g4) {
  u16* PA = Lc;          // [256][32]
  u16* PB = Lc + 8192;   // [128][32]
  bf16x8 a4[4], b4[4];

  // ph0: read A fm01 + B fn01; MFMA 2x2
#pragma unroll
  for (int fm = 0; fm < 2; fm++) a4[fm] = rdfrag(PA, wm * 64 + fm * 16 + r16, g4);
#pragma unroll
  for (int fn = 0; fn < 2; fn++) b4[fn] = rdfrag(PB, wn * 64 + fn * 16 + r16, g4);
  __builtin_amdgcn_s_barrier();
  asm volatile("s_waitcnt lgkmcnt(0)" ::: "memory");
  __builtin_amdgcn_s_setprio(1);
#pragma unroll
  for (int fm = 0; fm < 2; fm++)
#pragma unroll
    for (int fn = 0; fn < 2; fn++)
      acc[fm][fn] = __builtin_amdgcn_mfma_f32_16x16x32_bf16(a4[fm], b4[fn], acc[fm][fn], 0, 0, 0);
  __builtin_amdgcn_s_setprio(0);

  // ph1: read B fn23; MFMA fm01 x fn23
#pragma unroll
  for (int fn = 2; fn < 4; fn++) b4[fn] = rdfrag(PB, wn * 64 + fn * 16 + r16, g4);
  __builtin_amdgcn_s_barrier();
  asm volatile("s_waitcnt lgkmcnt(0)" ::: "memory");
  __builtin_amdgcn_s_setprio(1);
#pragma unroll
  for (int fm = 0; fm < 2; fm++)
#pragma unroll
    for (int fn = 2; fn < 4; fn++)
      acc[fm][fn] = __builtin_amdgcn_mfma_f32_16x16x32_bf16(a4[fm], b4[fn], acc[fm][fn], 0, 0, 0);
  __builtin_amdgcn_s_setprio(0);
  __builtin_amdgcn_s_barrier();  // B reads drained -> B plane free

  // ph2: read A fm23; stage next B; MFMA fm23 x fn01
#pragma unroll
  for (int fm = 2; fm < 4; fm++) a4[fm] = rdfrag(PA, wm * 64 + fm * 16 + r16, g4);
  if (STG) stage_half_sw(Bg + kst, PB, tid, NN);
  __builtin_amdgcn_s_barrier();
  asm volatile("s_waitcnt lgkmcnt(0)" ::: "memory");
  __builtin_amdgcn_s_setprio(1);
#pragma unroll
  for (int fm = 2; fm < 4; fm++)
#pragma unroll
    for (int fn = 0; fn < 2; fn++)
      acc[fm][fn] = __builtin_amdgcn_mfma_f32_16x16x32_bf16(a4[fm], b4[fn], acc[fm][fn], 0, 0, 0);
  __builtin_amdgcn_s_setprio(0);
  __builtin_amdgcn_s_barrier();  // A reads drained -> A plane free

  // ph3: stage next A; counted vmcnt; barrier; MFMA fm23 x fn23
  if (STG) stage_plane_sw(Ag + kst, PA, tid, PSTRIDE);
  if (VM == 3) {
    asm volatile("s_waitcnt vmcnt(3)" ::: "memory");
  } else if (VM == 0) {
    asm volatile("s_waitcnt vmcnt(0)" ::: "memory");
  }
  __builtin_amdgcn_s_barrier();
  __builtin_amdgcn_s_setprio(1);
#pragma unroll
  for (int fm = 2; fm < 4; fm++)
#pragma unroll
    for (int fn = 2; fn < 4; fn++)
      acc[fm][fn] = __builtin_amdgcn_mfma_f32_16x16x32_bf16(a4[fm], b4[fn], acc[fm][fn], 0, 0, 0);
  __builtin_amdgcn_s_setprio(0);
}

// ---- out[b] = P[b] @ Wout + bout. grid = nb*64 blocks of 512 -------------
__launch_bounds__(512, 2)
__global__ void k_gemm_out(const u16* __restrict__ P, const u16* __restrict__ woutT,
                           const float* __restrict__ bout, float* __restrict__ out) {
  __shared__ __attribute__((aligned(16))) u16 lds[2][12288];
  int wg = swz_wg();
  int b = wg >> 6, mt = (wg >> 3) & 7, nt = wg & 7;
  const u16* Ag = P + (size_t)b * NN * PSTRIDE + (size_t)(mt * 256) * PSTRIDE;
  const u16* Bg = woutT + (size_t)(nt * 128) * NN;
  float* ob = out + (size_t)b * NN * DD;

  int tid = threadIdx.x;
  int lane = tid & 63, r16 = lane & 15, g4 = lane >> 4;
  int w = tid >> 6, wm = w >> 1, wn = w & 1;
  u16* L0 = &lds[0][0];
  u16* L1 = &lds[1][0];

  f32x4 acc[4][4] = {};
  stage_plane_sw(Ag + 0, L0, tid, PSTRIDE);
  stage_half_sw(Bg + 0, L0 + 8192, tid, NN);
  stage_plane_sw(Ag + 32, L1, tid, PSTRIDE);
  stage_half_sw(Bg + 32, L1 + 8192, tid, NN);
  asm volatile("s_waitcnt vmcnt(3)" ::: "memory");
  __builtin_amdgcn_s_barrier();
#pragma unroll 1
  for (int i = 0; i < 31; i++) {  // K = 2048 -> 64 tiles
    int t0 = 2 * i;
    tile4q<true, 3>(L0, Ag, Bg, (t0 + 2) * 32, acc, tid, wm, wn, r16, g4);
    tile4q<true, 3>(L1, Ag, Bg, (t0 + 3) * 32, acc, tid, wm, wn, r16, g4);
  }
  tile4q<false, 0>(L0, Ag, Bg, 0, acc, tid, wm, wn, r16, g4);   // t=62
  tile4q<false, -1>(L1, Ag, Bg, 0, acc, tid, wm, wn, r16, g4);  // t=63

#pragma unroll
  for (int fm = 0; fm < 4; fm++)
#pragma unroll
    for (int fn = 0; fn < 4; fn++) {
      int col = nt * 128 + wn * 64 + fn * 16 + r16;  // d in [0,1024)
      float bv = bout[col];
      int row = mt * 256 + wm * 64 + fm * 16 + g4 * 4;
#pragma unroll
      for (int i2 = 0; i2 < 4; i2++)
        ob[(size_t)(row + i2) * DD + col] = acc[fm][fn][i2] + bv;
    }
}

// ---- prep: split fp32 -> hi/lo bf16 planes (weights) ---------------------
__global__ void k_split(const float* __restrict__ x, u16* __restrict__ hi,
                        u16* __restrict__ lo, long n4) {
  long i = (long)blockIdx.x * blockDim.x + threadIdx.x;
  long stride = (long)gridDim.x * blockDim.x;
  for (; i < n4; i += stride) {
    float4 v = ((const float4*)x)[i];
    u16 h0 = f2bf(v.x), h1 = f2bf(v.y), h2 = f2bf(v.z), h3 = f2bf(v.w);
    ushort4 hv; hv.x = h0; hv.y = h1; hv.z = h2; hv.w = h3;
    ushort4 lv;
    lv.x = f2bf(v.x - bf2f(h0)); lv.y = f2bf(v.y - bf2f(h1));
    lv.z = f2bf(v.z - bf2f(h2)); lv.w = f2bf(v.w - bf2f(h3));
    ((ushort4*)hi)[i] = hv;
    ((ushort4*)lo)[i] = lv;
  }
}

// ---- fused: split x rows into hi/lo planes AND c2[row] = x[row,:].v2 -----
__global__ void k_split_x(const float* __restrict__ x, const float* __restrict__ v2,
                          u16* __restrict__ hi, u16* __restrict__ lo,
                          float* __restrict__ c2) {
  int w = threadIdx.x >> 6, lane = threadIdx.x & 63;
  int row = blockIdx.x * 4 + w;
  const float4* xr = (const float4*)(x + (size_t)row * DD);
  const float4* vv = (const float4*)v2;
  ushort4* hr = (ushort4*)(hi + (size_t)row * DD);
  ushort4* lr = (ushort4*)(lo + (size_t)row * DD);
  float s = 0.f;
#pragma unroll
  for (int j = 0; j < 4; j++) {
    int idx = j * 64 + lane;
    float4 v = xr[idx];
    float4 b = vv[idx];
    s += v.x * b.x + v.y * b.y + v.z * b.z + v.w * b.w;
    u16 h0 = f2bf(v.x), h1 = f2bf(v.y), h2 = f2bf(v.z), h3 = f2bf(v.w);
    ushort4 hv; hv.x = h0; hv.y = h1; hv.z = h2; hv.w = h3;
    ushort4 lv;
    lv.x = f2bf(v.x - bf2f(h0)); lv.y = f2bf(v.y - bf2f(h1));
    lv.z = f2bf(v.z - bf2f(h2)); lv.w = f2bf(v.w - bf2f(h3));
    hr[idx] = hv;
    lr[idx] = lv;
  }
#pragma unroll
  for (int o = 32; o > 0; o >>= 1) s += __shfl_xor(s, o);
  if (lane == 0) c2[row] = s;
}

// ---- prep: transpose RxC fp32 -> CxR bf16 (hi only) ----------------------
__global__ void k_transpose_split(const float* __restrict__ W, u16* __restrict__ thi,
                                  int R, int C) {
  __shared__ float tile[32][33];
  int c0 = blockIdx.x * 32, r0 = blockIdx.y * 32;
  int tx = threadIdx.x, ty = threadIdx.y;  // block (32,8)
#pragma unroll
  for (int i = 0; i < 4; i++)
    tile[ty + i * 8][tx] = W[(size_t)(r0 + ty + i * 8) * C + c0 + tx];
  __syncthreads();
#pragma unroll
  for (int i = 0; i < 4; i++) {
    float v = tile[tx][ty + i * 8];
    thi[(size_t)(c0 + ty + i * 8) * R + r0 + tx] = f2bf(v);
  }
}

// ---- matvec: out[r] = A[r,:] . v  (wave per row) -------------------------
__global__ void k_matvec(const float* __restrict__ A, const float* __restrict__ v,
                         float* __restrict__ out, int cols) {
  int w = threadIdx.x >> 6, lane = threadIdx.x & 63;
  int row = blockIdx.x * 4 + w;
  const float4* Ar = (const float4*)(A + (size_t)row * cols);
  const float4* vv = (const float4*)v;
  float s = 0.f;
  for (int j = lane; j < cols / 4; j += 64) {
    float4 a = Ar[j], b = vv[j];
    s += a.x * b.x + a.y * b.y + a.z * b.z + a.w * b.w;
  }
#pragma unroll
  for (int o = 32; o > 0; o >>= 1) s += __shfl_xor(s, o);
  if (lane == 0) out[row] = s;
}

// ---- softmax rows of S (+ per-col bias c2) -> P bf16 IN PLACE ------------
__global__ void k_softmax(float* __restrict__ S, const float* __restrict__ c2, int nrows) {
  int w = threadIdx.x >> 6, lane = threadIdx.x & 63;
  int row = blockIdx.x * 4 + w;
  if (row >= nrows) return;
  const float4* Sr = (const float4*)(S + (size_t)row * NN);
  const float4* c2b = (const float4*)(c2 + ((size_t)(row >> 11) << 11));
  float4 v[8];
  float mx = -3.4e38f;
#pragma unroll
  for (int j = 0; j < 8; j++) {
    v[j] = Sr[j * 64 + lane];
    float4 c = c2b[j * 64 + lane];
    v[j].x += c.x; v[j].y += c.y; v[j].z += c.z; v[j].w += c.w;
    mx = fmaxf(mx, fmaxf(fmaxf(v[j].x, v[j].y), fmaxf(v[j].z, v[j].w)));
  }
#pragma unroll
  for (int o = 32; o > 0; o >>= 1) mx = fmaxf(mx, __shfl_xor(mx, o));
  float e[32];
  float sum = 0.f;
#pragma unroll
  for (int j = 0; j < 8; j++) {
    e[j * 4 + 0] = __expf(v[j].x - mx);
    e[j * 4 + 1] = __expf(v[j].y - mx);
    e[j * 4 + 2] = __expf(v[j].z - mx);
    e[j * 4 + 3] = __expf(v[j].w - mx);
    sum += e[j * 4 + 0] + e[j * 4 + 1] + e[j * 4 + 2] + e[j * 4 + 3];
  }
#pragma unroll
  for (int o = 32; o > 0; o >>= 1) sum += __shfl_xor(sum, o);
  float inv = 1.0f / sum;  // depends on every lane's loads -> safe to overwrite row
  ushort4* Pr = (ushort4*)((u16*)S + (size_t)row * PSTRIDE);
#pragma unroll
  for (int j = 0; j < 8; j++) {
    ushort4 pv;
    pv.x = f2bf(e[j * 4 + 0] * inv);
    pv.y = f2bf(e[j * 4 + 1] * inv);
    pv.z = f2bf(e[j * 4 + 2] * inv);
    pv.w = f2bf(e[j * 4 + 3] * inv);
    Pr[j * 64 + lane] = pv;
  }
}

extern "C" void kernel_launch(void* const* d_in, const int* in_sizes, int n_in,
                              void* d_out, int out_size, void* d_ws, size_t ws_size,
                              hipStream_t stream) {
  const float* x = (const float*)d_in[0];
  const float* Wq = (const float*)d_in[1];
  const float* bq = (const float*)d_in[2];
  const float* Wk = (const float*)d_in[3];
  const float* bk = (const float*)d_in[4];
  const float* Wout = (const float*)d_in[5];
  const float* bout = (const float*)d_in[6];
  float* out = (float*)d_out;
  char* ws = (char*)d_ws;

  const size_t MB = 1ull << 20;
  u16* mth = (u16*)(ws + 0 * MB);
  u16* mtl = (u16*)(ws + 2 * MB);
  u16* woutT = (u16*)(ws + 4 * MB);            // 4 MiB [1024][2048]
  float* v2 = (float*)(ws + 8 * MB);           // 4 KiB
  float* c2 = (float*)(ws + 8 * MB + 65536);   // 64 KiB
  char* base = ws + 12 * MB;

  dim3 tb(32, 8, 1);

  if (ws_size >= 204 * MB) {
    // Tier A: xh/xl [0,64), yh/yl [64,128), S/scratch [128,192)
    u16* xh = (u16*)(base);
    u16* xl = (u16*)(base + 32 * MB);
    u16* yh = (u16*)(base + 64 * MB);
    u16* yl = (u16*)(base + 96 * MB);
    char* R = base + 128 * MB;  // 64 MiB scratch: W planes + Mt partials, then S
    u16* wqh = (u16*)(R);
    u16* wql = (u16*)(R + 2 * MB);
    u16* wkh = (u16*)(R + 4 * MB);
    u16* wkl = (u16*)(R + 6 * MB);
    float* mtp = (float*)(R + 8 * MB);  // 16 MiB partials
    float* S = (float*)R;

    // prep
    k_split<<<256, 256, 0, stream>>>(Wq, wqh, wql, (long)DD * DD / 4);
    k_split<<<256, 256, 0, stream>>>(Wk, wkh, wkl, (long)DD * DD / 4);
    k_gemm_mt<<<256, 256, 0, stream>>>(wkh, wkl, wqh, wql, mtp);
    k_combine_split<<<256, 256, 0, stream>>>(mtp, mth, mtl);
    k_transpose_split<<<dim3(32, 64, 1), tb, 0, stream>>>(Wout, woutT, 2048, 1024);
    k_matvec<<<256, 256, 0, stream>>>(Wk, bq, v2, DD);
    k_split_x<<<MT / 4, 256, 0, stream>>>(x, v2, xh, xl, c2);
    // y = x @ Mt^T  (skewed 128^2 core, A/B vs s8's 256^2 core)
    k_gemm_y8<<<1024, 256, 0, stream>>>(xh, xl, mth, mtl, yh, yl);
    // per 4-batch half: S, softmax, out
    for (int h = 0; h < 2; h++) {
      size_t qo = (size_t)h * 4 * NN * DD;
      k_gemm_s8<<<256, 512, 0, stream>>>(yh + qo, yl + qo, xh + qo, xl + qo, S);
      k_softmax<<<4 * NN / 4, 256, 0, stream>>>(S, c2 + (size_t)h * 4 * NN, 4 * NN);
      k_gemm_out<<<256, 512, 0, stream>>>((const u16*)S, woutT, bout, out + qo);
    }
  } else if (ws_size >= 156 * MB) {
    // Tier B: xh/xl [0,64), yh/yl [64,128), S 16MB at [128,144)
    u16* xh = (u16*)(base);
    u16* xl = (u16*)(base + 32 * MB);
    u16* yh = (u16*)(base + 64 * MB);
    u16* yl = (u16*)(base + 96 * MB);
    char* R = base + 128 * MB;
    u16* wqh = (u16*)(R);
    u16* wql = (u16*)(R + 2 * MB);
    u16* wkh = (u16*)(R + 4 * MB);
    u16* wkl = (u16*)(R + 6 * MB);
    float* mtp = (float*)yh;  // 16 MiB partials in (not-yet-written) yh region
    float* S = (float*)R;

    k_split<<<256, 256, 0, stream>>>(Wq, wqh, wql, (long)DD * DD / 4);
    k_split<<<256, 256, 0, stream>>>(Wk, wkh, wkl, (long)DD * DD / 4);
    k_gemm_mt<<<256, 256, 0, stream>>>(wkh, wkl, wqh, wql, mtp);
    k_combine_split<<<256, 256, 0, stream>>>(mtp, mth, mtl);
    k_transpose_split<<<dim3(32, 64, 1), tb, 0, stream>>>(Wout, woutT, 2048, 1024);
    k_matvec<<<256, 256, 0, stream>>>(Wk, bq, v2, DD);
    k_split_x<<<MT / 4, 256, 0, stream>>>(x, v2, xh, xl, c2);
    k_gemm_y8<<<1024, 256, 0, stream>>>(xh, xl, mth, mtl, yh, yl);
    for (int b = 0; b < BB; b++) {
      size_t qo = (size_t)b * NN * DD;
      k_gemm_s8<<<64, 512, 0, stream>>>(yh + qo, yl + qo, xh + qo, xl + qo, S);
      k_softmax<<<NN / 4, 256, 0, stream>>>(S, c2 + (size_t)b * NN, NN);
      k_gemm_out<<<64, 512, 0, stream>>>((const u16*)S, woutT, bout, out + qo);
    }
  } else {
    // Tier C (60 MiB): per 2-batch chunk, xh/xl 16MB, yh/yl 16MB, S 16MB
    u16* xh = (u16*)(base);
    u16* xl = (u16*)(base + 8 * MB);
    u16* yh = (u16*)(base + 16 * MB);
    u16* yl = (u16*)(base + 24 * MB);
    char* R = base + 32 * MB;
    u16* wqh = (u16*)(R);
    u16* wql = (u16*)(R + 2 * MB);
    u16* wkh = (u16*)(R + 4 * MB);
    u16* wkl = (u16*)(R + 6 * MB);
    float* mtp = (float*)yh;  // 16 MiB partials in yh region (written later)
    float* S = (float*)R;

    k_split<<<256, 256, 0, stream>>>(Wq, wqh, wql, (long)DD * DD / 4);
    k_split<<<256, 256, 0, stream>>>(Wk, wkh, wkl, (long)DD * DD / 4);
    k_gemm_mt<<<256, 256, 0, stream>>>(wkh, wkl, wqh, wql, mtp);
    k_combine_split<<<256, 256, 0, stream>>>(mtp, mth, mtl);
    k_transpose_split<<<dim3(32, 64, 1), tb, 0, stream>>>(Wout, woutT, 2048, 1024);
    k_matvec<<<256, 256, 0, stream>>>(Wk, bq, v2, DD);
    for (int c = 0; c < 4; c++) {
      size_t xo = (size_t)c * 2 * NN * DD;
      k_split_x<<<2 * NN / 4, 256, 0, stream>>>(x + xo, v2, xh, xl, c2 + (size_t)c * 2 * NN);
      k_gemm_y8<<<256, 256, 0, stream>>>(xh, xl, mth, mtl, yh, yl);
      for (int bi = 0; bi < 2; bi++) {
        size_t lo = (size_t)bi * NN * DD;
        k_gemm_s8<<<64, 512, 0, stream>>>(yh + lo, yl + lo, xh + lo, xl + lo, S);
        k_softmax<<<NN / 4, 256, 0, stream>>>(S, c2 + (size_t)(c * 2 + bi) * NN, NN);
        k_gemm_out<<<64, 512, 0, stream>>>((const u16*)S, woutT, bout, out + xo + lo);
      }
    }
  }
}

// Round 16
// 438.398 us; speedup vs baseline: 1.0877x; 1.0244x over previous
//
#include <hip/hip_runtime.h>

// SelfAttention: out = softmax((xWq+bq)(xWk+bk)^T) @ Wout + bout
// B=8, N=2048, D=1024, fp32 in/out.
// Round 16: FINAL — revert to the best-measured configuration (round 9,
// 438.7us). Six subsequent scheduling variants (barrier/drain/ILP/32x32/
// dual-block/skew) all confirmed an invariant ~46us MFMA-busy per 103GF
// dispatch with no net gain; this structure is at its practical ceiling.
// S = x(WqWk^T)x^T algebraic form; score chain bf16 hi/lo split (3 MFMAs);
// P@Wout plain bf16 256x128 pipelined core; K-sliced Mt prep; fused x-split.

typedef unsigned short u16;
typedef __bf16 bf16x8 __attribute__((ext_vector_type(8)));
typedef float f32x4 __attribute__((ext_vector_type(4)));

#define BB 8
#define NN 2048
#define DD 1024
#define MT (BB * NN)
#define PSTRIDE 4096  // u16 elems per P row (in-place over fp32 S rows)

#define MFMA3(d, ah, al, bh, bl)                                         \
  d = __builtin_amdgcn_mfma_f32_16x16x32_bf16(ah, bh, d, 0, 0, 0);       \
  d = __builtin_amdgcn_mfma_f32_16x16x32_bf16(ah, bl, d, 0, 0, 0);       \
  d = __builtin_amdgcn_mfma_f32_16x16x32_bf16(al, bh, d, 0, 0, 0);

static __device__ __forceinline__ u16 f2bf(float f) {
  unsigned u = __builtin_bit_cast(unsigned, f);
  u += 0x7FFFu + ((u >> 16) & 1u);
  return (u16)(u >> 16);
}
static __device__ __forceinline__ float bf2f(u16 h) {
  unsigned u = ((unsigned)h) << 16;
  return __builtin_bit_cast(float, u);
}

static __device__ __forceinline__ void gload16(const void* g, void* l) {
  __builtin_amdgcn_global_load_lds((const __attribute__((address_space(1))) void*)g,
                                   (__attribute__((address_space(3))) void*)l, 16, 0, 0);
}

// bijective XCD swizzle over a 1-D grid (gridDim.x % 8 == 0 for all callers)
static __device__ __forceinline__ int swz_wg() {
  int nwg = gridDim.x;
  int orig = blockIdx.x;
  int q = nwg >> 3;
  return (orig & 7) * q + (orig >> 3);
}

// ---------------- shared LDS swizzle helpers ------------------------------
// XOR-swizzle (T2): 16B chunk c of row r stored at c ^ ((r ^ r>>2) & 3).
#define SW(r) (((r) ^ ((r) >> 2)) & 3)

// stage a [256][32]-u16 plane, generic row stride ld (2 gloads/thread @512t)
static __device__ __forceinline__ void stage_plane_sw(const u16* __restrict__ g0,
                                                      u16* lp0, int tid, int ld) {
#pragma unroll
  for (int j = 0; j < 2; j++) {
    int o = tid + j * 512;  // 16B-chunk index 0..1023 within plane
    int row = o >> 2, c = o & 3;
    const u16* g = g0 + (size_t)row * ld + ((c ^ SW(row)) << 3);  // inverse-swz src
    u16* lp = lp0 + (((tid >> 6) << 6) + j * 512) * 8;  // wave-uniform; HW adds lane*16B
    gload16(g, lp);
  }
}

// stage a [128][32]-u16 plane (1 gload/thread @512t)
static __device__ __forceinline__ void stage_half_sw(const u16* __restrict__ g0,
                                                     u16* lp0, int tid, int ld) {
  int o = tid;  // chunk 0..511
  int row = o >> 2, c = o & 3;
  const u16* g = g0 + (size_t)row * ld + ((c ^ SW(row)) << 3);
  u16* lp = lp0 + ((tid >> 6) << 6) * 8;
  gload16(g, lp);
}

static __device__ __forceinline__ bf16x8 rdfrag(const u16* plane, int row, int g4) {
  return *(const bf16x8*)&plane[row * 32 + ((g4 ^ SW(row)) << 3)];
}

// ---------------- 256x256 pipelined split-GEMM core -----------------------
template <bool STG, int VM>
static __device__ __forceinline__ void tile4(
    u16* Lc, const u16* Ah, const u16* Al, const u16* Bh, const u16* Bl, int kst,
    f32x4 (&acc)[8][4], int tid, int wm, int wn, int r16, int g4) {
  u16* PA0 = Lc;
  u16* PA1 = Lc + 8192;
  u16* PB0 = Lc + 16384;
  u16* PB1 = Lc + 24576;
  bf16x8 a0[4], a1[4], b0[4], b1[4];

  // ---- phase 0: read A-half0 + B(n0-1); MFMA (m0, n0-1)
#pragma unroll
  for (int fm = 0; fm < 4; fm++) {
    int rw = wm * 128 + fm * 16 + r16;
    a0[fm] = rdfrag(PA0, rw, g4);
    a1[fm] = rdfrag(PA1, rw, g4);
  }
#pragma unroll
  for (int fn = 0; fn < 2; fn++) {
    int rw = wn * 64 + fn * 16 + r16;
    b0[fn] = rdfrag(PB0, rw, g4);
    b1[fn] = rdfrag(PB1, rw, g4);
  }
  __builtin_amdgcn_s_barrier();
  asm volatile("s_waitcnt lgkmcnt(0)" ::: "memory");
  __builtin_amdgcn_s_setprio(1);
#pragma unroll
  for (int fm = 0; fm < 4; fm++)
#pragma unroll
    for (int fn = 0; fn < 2; fn++) { MFMA3(acc[fm][fn], a0[fm], a1[fm], b0[fn], b1[fn]); }
  __builtin_amdgcn_s_setprio(0);

  // ---- phase 1: read B(n2-3); MFMA (m0, n2-3)
#pragma unroll
  for (int fn = 2; fn < 4; fn++) {
    int rw = wn * 64 + fn * 16 + r16;
    b0[fn] = rdfrag(PB0, rw, g4);
    b1[fn] = rdfrag(PB1, rw, g4);
  }
  __builtin_amdgcn_s_barrier();
  asm volatile("s_waitcnt lgkmcnt(0)" ::: "memory");
  __builtin_amdgcn_s_setprio(1);
#pragma unroll
  for (int fm = 0; fm < 4; fm++)
#pragma unroll
    for (int fn = 2; fn < 4; fn++) { MFMA3(acc[fm][fn], a0[fm], a1[fm], b0[fn], b1[fn]); }
  __builtin_amdgcn_s_setprio(0);
  __builtin_amdgcn_s_barrier();  // all waves' B reads drained -> B planes free

  // ---- phase 2: read A-half1; stage next B planes; MFMA (m1, n0-1)
#pragma unroll
  for (int fm = 0; fm < 4; fm++) {
    int rw = wm * 128 + 64 + fm * 16 + r16;
    a0[fm] = rdfrag(PA0, rw, g4);
    a1[fm] = rdfrag(PA1, rw, g4);
  }
  if (STG) {
    stage_plane_sw(Bh + kst, PB0, tid, DD);
    stage_plane_sw(Bl + kst, PB1, tid, DD);
  }
  __builtin_amdgcn_s_barrier();
  asm volatile("s_waitcnt lgkmcnt(0)" ::: "memory");
  __builtin_amdgcn_s_setprio(1);
#pragma unroll
  for (int fm = 0; fm < 4; fm++)
#pragma unroll
    for (int fn = 0; fn < 2; fn++) { MFMA3(acc[fm + 4][fn], a0[fm], a1[fm], b0[fn], b1[fn]); }
  __builtin_amdgcn_s_setprio(0);
  __builtin_amdgcn_s_barrier();  // all waves' A reads drained -> A planes free

  // ---- phase 3: stage next A planes; counted vmcnt; barrier; MFMA (m1, n2-3)
  if (STG) {
    stage_plane_sw(Ah + kst, PA0, tid, DD);
    stage_plane_sw(Al + kst, PA1, tid, DD);
  }
  if (VM == 8) {
    asm volatile("s_waitcnt vmcnt(8)" ::: "memory");
  } else if (VM == 0) {
    asm volatile("s_waitcnt vmcnt(0)" ::: "memory");
  }
  __builtin_amdgcn_s_barrier();  // next tile's buffer fully landed for all
  __builtin_amdgcn_s_setprio(1);
#pragma unroll
  for (int fm = 0; fm < 4; fm++)
#pragma unroll
    for (int fn = 2; fn < 4; fn++) { MFMA3(acc[fm + 4][fn], a0[fm], a1[fm], b0[fn], b1[fn]); }
  __builtin_amdgcn_s_setprio(0);
}

static __device__ __forceinline__ void mm8_core(u16* L, const u16* Ah, const u16* Al,
                                                const u16* Bh, const u16* Bl,
                                                f32x4 (&acc)[8][4], int tid) {
  int lane = tid & 63, r16 = lane & 15, g4 = lane >> 4;
  int w = tid >> 6, wm = w >> 2, wn = w & 3;
  u16* L0 = L;
  u16* L1 = L + 4 * 8192;
  stage_plane_sw(Ah + 0, L0 + 0, tid, DD);
  stage_plane_sw(Al + 0, L0 + 8192, tid, DD);
  stage_plane_sw(Bh + 0, L0 + 16384, tid, DD);
  stage_plane_sw(Bl + 0, L0 + 24576, tid, DD);
  stage_plane_sw(Ah + 32, L1 + 0, tid, DD);
  stage_plane_sw(Al + 32, L1 + 8192, tid, DD);
  stage_plane_sw(Bh + 32, L1 + 16384, tid, DD);
  stage_plane_sw(Bl + 32, L1 + 24576, tid, DD);
  asm volatile("s_waitcnt vmcnt(8)" ::: "memory");
  __builtin_amdgcn_s_barrier();
#pragma unroll 1
  for (int i = 0; i < 15; i++) {
    int t0 = 2 * i;
    tile4<true, 8>(L0, Ah, Al, Bh, Bl, (t0 + 2) * 32, acc, tid, wm, wn, r16, g4);
    tile4<true, 8>(L1, Ah, Al, Bh, Bl, (t0 + 3) * 32, acc, tid, wm, wn, r16, g4);
  }
  tile4<false, 0>(L0, Ah, Al, Bh, Bl, 0, acc, tid, wm, wn, r16, g4);   // t=30
  tile4<false, -1>(L1, Ah, Al, Bh, Bl, 0, acc, tid, wm, wn, r16, g4);  // t=31
}

// ---- S[b] = y[b] @ x[b]^T (fp32 out). grid = nb*64 blocks of 512 ---------
__launch_bounds__(512, 2)
__global__ void k_gemm_s8(const u16* __restrict__ yh, const u16* __restrict__ yl,
                          const u16* __restrict__ xh, const u16* __restrict__ xl,
                          float* __restrict__ S) {
  __shared__ __attribute__((aligned(16))) u16 lds[2][4][8192];
  int wg = swz_wg();
  int nt = wg & 7, mtot = wg >> 3;
  int b = mtot >> 3, mt = mtot & 7;
  const size_t po = (size_t)b * NN * DD;
  const u16* Ah = yh + po + (size_t)(mt * 256) * DD;
  const u16* Al = yl + po + (size_t)(mt * 256) * DD;
  const u16* Bh = xh + po + (size_t)(nt * 256) * DD;
  const u16* Bl = xl + po + (size_t)(nt * 256) * DD;
  int tid = threadIdx.x;
  f32x4 acc[8][4] = {};
  mm8_core(&lds[0][0][0], Ah, Al, Bh, Bl, acc, tid);
  int lane = tid & 63, r16 = lane & 15, g4 = lane >> 4;
  int w = tid >> 6, wm = w >> 2, wn = w & 3;
  float* Sb = S + (size_t)b * NN * NN;
#pragma unroll
  for (int fm = 0; fm < 8; fm++)
#pragma unroll
    for (int fn = 0; fn < 4; fn++) {
      int col = nt * 256 + wn * 64 + fn * 16 + r16;
      int row = mt * 256 + wm * 128 + fm * 16 + g4 * 4;
#pragma unroll
      for (int i2 = 0; i2 < 4; i2++)
        Sb[(size_t)(row + i2) * NN + col] = acc[fm][fn][i2];
    }
}

// ---- C = A @ B^T with split bf16 planes out (y GEMM) ---------------------
__launch_bounds__(512, 2)
__global__ void k_gemm_y8(const u16* __restrict__ ah_g, const u16* __restrict__ al_g,
                          const u16* __restrict__ bh_g, const u16* __restrict__ bl_g,
                          u16* __restrict__ ohi, u16* __restrict__ olo) {
  __shared__ __attribute__((aligned(16))) u16 lds[2][4][8192];
  int wg = swz_wg();
  int nt = wg & 3, mt = wg >> 2;
  const u16* Ah = ah_g + (size_t)(mt * 256) * DD;
  const u16* Al = al_g + (size_t)(mt * 256) * DD;
  const u16* Bh = bh_g + (size_t)(nt * 256) * DD;
  const u16* Bl = bl_g + (size_t)(nt * 256) * DD;
  int tid = threadIdx.x;
  f32x4 acc[8][4] = {};
  mm8_core(&lds[0][0][0], Ah, Al, Bh, Bl, acc, tid);
  int lane = tid & 63, r16 = lane & 15, g4 = lane >> 4;
  int w = tid >> 6, wm = w >> 2, wn = w & 3;
#pragma unroll
  for (int fm = 0; fm < 8; fm++)
#pragma unroll
    for (int fn = 0; fn < 4; fn++) {
      int col = nt * 256 + wn * 64 + fn * 16 + r16;
      int row = mt * 256 + wm * 128 + fm * 16 + g4 * 4;
#pragma unroll
      for (int i2 = 0; i2 < 4; i2++) {
        float v = acc[fm][fn][i2];
        u16 h = f2bf(v);
        size_t o = (size_t)(row + i2) * DD + col;
        ohi[o] = h;
        olo[o] = f2bf(v - bf2f(h));
      }
    }
}

// ---------------- Mt prep: K-sliced 128^2 split GEMM ----------------------
static __device__ __forceinline__ void stage128_lin(const u16* __restrict__ g0,
                                                    u16* lp0, int tid, int ld) {
#pragma unroll
  for (int j = 0; j < 2; j++) {
    int o = tid + j * 256;  // chunk 0..511
    const u16* g = g0 + (size_t)(o >> 2) * ld + (o & 3) * 8;
    u16* lp = lp0 + (((tid >> 6) << 6) + j * 256) * 8;
    gload16(g, lp);
  }
}

__launch_bounds__(256)
__global__ void k_gemm_mt(const u16* __restrict__ wkh, const u16* __restrict__ wkl,
                          const u16* __restrict__ wqh, const u16* __restrict__ wql,
                          float* __restrict__ part) {
  __shared__ __attribute__((aligned(16))) u16 lds[4][128][32];
  int idx = blockIdx.x;
  int ks = idx >> 6, mt = (idx >> 3) & 7, nt = idx & 7;
  int t = threadIdx.x, lane = t & 63, w = t >> 6;
  int wr = w >> 1, wc = w & 1, r16 = lane & 15, g = lane >> 4;
  const u16* Ah = wkh + (size_t)(mt * 128) * DD;
  const u16* Al = wkl + (size_t)(mt * 128) * DD;
  const u16* Bh = wqh + (size_t)(nt * 128) * DD;
  const u16* Bl = wql + (size_t)(nt * 128) * DD;
  float* P = part + (size_t)ks * DD * DD;

  f32x4 acc[4][4] = {};
  for (int k0 = ks * 256; k0 < ks * 256 + 256; k0 += 32) {
    stage128_lin(Ah + k0, &lds[0][0][0], t, DD);
    stage128_lin(Al + k0, &lds[1][0][0], t, DD);
    stage128_lin(Bh + k0, &lds[2][0][0], t, DD);
    stage128_lin(Bl + k0, &lds[3][0][0], t, DD);
    asm volatile("s_waitcnt vmcnt(0)" ::: "memory");
    __syncthreads();
    bf16x8 bh[4], bl[4];
#pragma unroll
    for (int fn = 0; fn < 4; fn++) {
      int col = wc * 64 + fn * 16 + r16;
      bh[fn] = *(const bf16x8*)&lds[2][col][g * 8];
      bl[fn] = *(const bf16x8*)&lds[3][col][g * 8];
    }
#pragma unroll
    for (int fm = 0; fm < 4; fm++) {
      int row = wr * 64 + fm * 16 + r16;
      bf16x8 ah = *(const bf16x8*)&lds[0][row][g * 8];
      bf16x8 al = *(const bf16x8*)&lds[1][row][g * 8];
#pragma unroll
      for (int fn = 0; fn < 4; fn++) { MFMA3(acc[fm][fn], ah, al, bh[fn], bl[fn]); }
    }
    __syncthreads();
  }
#pragma unroll
  for (int fm = 0; fm < 4; fm++)
#pragma unroll
    for (int fn = 0; fn < 4; fn++) {
      int col = nt * 128 + wc * 64 + fn * 16 + r16;
      int row = mt * 128 + wr * 64 + fm * 16 + g * 4;
#pragma unroll
      for (int i = 0; i < 4; i++)
        P[(size_t)(row + i) * DD + col] = acc[fm][fn][i];
    }
}

// combine 4 partial slices + split to hi/lo bf16 planes
__global__ void k_combine_split(const float* __restrict__ part, u16* __restrict__ hi,
                                u16* __restrict__ lo) {
  const long n4 = (long)DD * DD / 4;
  long i = (long)blockIdx.x * blockDim.x + threadIdx.x;
  long stride = (long)gridDim.x * blockDim.x;
  const float4* p0 = (const float4*)part;
  const float4* p1 = (const float4*)(part + (size_t)DD * DD);
  const float4* p2 = (const float4*)(part + (size_t)2 * DD * DD);
  const float4* p3 = (const float4*)(part + (size_t)3 * DD * DD);
  for (; i < n4; i += stride) {
    float4 a = p0[i], b = p1[i], c = p2[i], d = p3[i];
    float4 v;
    v.x = a.x + b.x + c.x + d.x;
    v.y = a.y + b.y + c.y + d.y;
    v.z = a.z + b.z + c.z + d.z;
    v.w = a.w + b.w + c.w + d.w;
    u16 h0 = f2bf(v.x), h1 = f2bf(v.y), h2 = f2bf(v.z), h3 = f2bf(v.w);
    ushort4 hv; hv.x = h0; hv.y = h1; hv.z = h2; hv.w = h3;
    ushort4 lv;
    lv.x = f2bf(v.x - bf2f(h0)); lv.y = f2bf(v.y - bf2f(h1));
    lv.z = f2bf(v.z - bf2f(h2)); lv.w = f2bf(v.w - bf2f(h3));
    ((ushort4*)hi)[i] = hv;
    ((ushort4*)lo)[i] = lv;
  }
}

// ---------------- 256x128 pipelined PLAIN-bf16 out core -------------------
template <bool STG, int VM>
static __device__ __forceinline__ void tile4q(
    u16* Lc, const u16* Ag, const u16* Bg, int kst,
    f32x4 (&acc)[4][4], int tid, int wm, int wn, int r16, int g4) {
  u16* PA = Lc;          // [256][32]
  u16* PB = Lc + 8192;   // [128][32]
  bf16x8 a4[4], b4[4];

  // ph0: read A fm01 + B fn01; MFMA 2x2
#pragma unroll
  for (int fm = 0; fm < 2; fm++) a4[fm] = rdfrag(PA, wm * 64 + fm * 16 + r16, g4);
#pragma unroll
  for (int fn = 0; fn < 2; fn++) b4[fn] = rdfrag(PB, wn * 64 + fn * 16 + r16, g4);
  __builtin_amdgcn_s_barrier();
  asm volatile("s_waitcnt lgkmcnt(0)" ::: "memory");
  __builtin_amdgcn_s_setprio(1);
#pragma unroll
  for (int fm = 0; fm < 2; fm++)
#pragma unroll
    for (int fn = 0; fn < 2; fn++)
      acc[fm][fn] = __builtin_amdgcn_mfma_f32_16x16x32_bf16(a4[fm], b4[fn], acc[fm][fn], 0, 0, 0);
  __builtin_amdgcn_s_setprio(0);

  // ph1: read B fn23; MFMA fm01 x fn23
#pragma unroll
  for (int fn = 2; fn < 4; fn++) b4[fn] = rdfrag(PB, wn * 64 + fn * 16 + r16, g4);
  __builtin_amdgcn_s_barrier();
  asm volatile("s_waitcnt lgkmcnt(0)" ::: "memory");
  __builtin_amdgcn_s_setprio(1);
#pragma unroll
  for (int fm = 0; fm < 2; fm++)
#pragma unroll
    for (int fn = 2; fn < 4; fn++)
      acc[fm][fn] = __builtin_amdgcn_mfma_f32_16x16x32_bf16(a4[fm], b4[fn], acc[fm][fn], 0, 0, 0);
  __builtin_amdgcn_s_setprio(0);
  __builtin_amdgcn_s_barrier();  // B reads drained -> B plane free

  // ph2: read A fm23; stage next B; MFMA fm23 x fn01
#pragma unroll
  for (int fm = 2; fm < 4; fm++) a4[fm] = rdfrag(PA, wm * 64 + fm * 16 + r16, g4);
  if (STG) stage_half_sw(Bg + kst, PB, tid, NN);
  __builtin_amdgcn_s_barrier();
  asm volatile("s_waitcnt lgkmcnt(0)" ::: "memory");
  __builtin_amdgcn_s_setprio(1);
#pragma unroll
  for (int fm = 2; fm < 4; fm++)
#pragma unroll
    for (int fn = 0; fn < 2; fn++)
      acc[fm][fn] = __builtin_amdgcn_mfma_f32_16x16x32_bf16(a4[fm], b4[fn], acc[fm][fn], 0, 0, 0);
  __builtin_amdgcn_s_setprio(0);
  __builtin_amdgcn_s_barrier();  // A reads drained -> A plane free

  // ph3: stage next A; counted vmcnt; barrier; MFMA fm23 x fn23
  if (STG) stage_plane_sw(Ag + kst, PA, tid, PSTRIDE);
  if (VM == 3) {
    asm volatile("s_waitcnt vmcnt(3)" ::: "memory");
  } else if (VM == 0) {
    asm volatile("s_waitcnt vmcnt(0)" ::: "memory");
  }
  __builtin_amdgcn_s_barrier();
  __builtin_amdgcn_s_setprio(1);
#pragma unroll
  for (int fm = 2; fm < 4; fm++)
#pragma unroll
    for (int fn = 2; fn < 4; fn++)
      acc[fm][fn] = __builtin_amdgcn_mfma_f32_16x16x32_bf16(a4[fm], b4[fn], acc[fm][fn], 0, 0, 0);
  __builtin_amdgcn_s_setprio(0);
}

// ---- out[b] = P[b] @ Wout + bout. grid = nb*64 blocks of 512 -------------
__launch_bounds__(512, 2)
__global__ void k_gemm_out(const u16* __restrict__ P, const u16* __restrict__ woutT,
                           const float* __restrict__ bout, float* __restrict__ out) {
  __shared__ __attribute__((aligned(16))) u16 lds[2][12288];
  int wg = swz_wg();
  int b = wg >> 6, mt = (wg >> 3) & 7, nt = wg & 7;
  const u16* Ag = P + (size_t)b * NN * PSTRIDE + (size_t)(mt * 256) * PSTRIDE;
  const u16* Bg = woutT + (size_t)(nt * 128) * NN;
  float* ob = out + (size_t)b * NN * DD;

  int tid = threadIdx.x;
  int lane = tid & 63, r16 = lane & 15, g4 = lane >> 4;
  int w = tid >> 6, wm = w >> 1, wn = w & 1;
  u16* L0 = &lds[0][0];
  u16* L1 = &lds[1][0];

  f32x4 acc[4][4] = {};
  stage_plane_sw(Ag + 0, L0, tid, PSTRIDE);
  stage_half_sw(Bg + 0, L0 + 8192, tid, NN);
  stage_plane_sw(Ag + 32, L1, tid, PSTRIDE);
  stage_half_sw(Bg + 32, L1 + 8192, tid, NN);
  asm volatile("s_waitcnt vmcnt(3)" ::: "memory");
  __builtin_amdgcn_s_barrier();
#pragma unroll 1
  for (int i = 0; i < 31; i++) {  // K = 2048 -> 64 tiles
    int t0 = 2 * i;
    tile4q<true, 3>(L0, Ag, Bg, (t0 + 2) * 32, acc, tid, wm, wn, r16, g4);
    tile4q<true, 3>(L1, Ag, Bg, (t0 + 3) * 32, acc, tid, wm, wn, r16, g4);
  }
  tile4q<false, 0>(L0, Ag, Bg, 0, acc, tid, wm, wn, r16, g4);   // t=62
  tile4q<false, -1>(L1, Ag, Bg, 0, acc, tid, wm, wn, r16, g4);  // t=63

#pragma unroll
  for (int fm = 0; fm < 4; fm++)
#pragma unroll
    for (int fn = 0; fn < 4; fn++) {
      int col = nt * 128 + wn * 64 + fn * 16 + r16;  // d in [0,1024)
      float bv = bout[col];
      int row = mt * 256 + wm * 64 + fm * 16 + g4 * 4;
#pragma unroll
      for (int i2 = 0; i2 < 4; i2++)
        ob[(size_t)(row + i2) * DD + col] = acc[fm][fn][i2] + bv;
    }
}

// ---- prep: split fp32 -> hi/lo bf16 planes (weights) ---------------------
__global__ void k_split(const float* __restrict__ x, u16* __restrict__ hi,
                        u16* __restrict__ lo, long n4) {
  long i = (long)blockIdx.x * blockDim.x + threadIdx.x;
  long stride = (long)gridDim.x * blockDim.x;
  for (; i < n4; i += stride) {
    float4 v = ((const float4*)x)[i];
    u16 h0 = f2bf(v.x), h1 = f2bf(v.y), h2 = f2bf(v.z), h3 = f2bf(v.w);
    ushort4 hv; hv.x = h0; hv.y = h1; hv.z = h2; hv.w = h3;
    ushort4 lv;
    lv.x = f2bf(v.x - bf2f(h0)); lv.y = f2bf(v.y - bf2f(h1));
    lv.z = f2bf(v.z - bf2f(h2)); lv.w = f2bf(v.w - bf2f(h3));
    ((ushort4*)hi)[i] = hv;
    ((ushort4*)lo)[i] = lv;
  }
}

// ---- fused: split x rows into hi/lo planes AND c2[row] = x[row,:].v2 -----
__global__ void k_split_x(const float* __restrict__ x, const float* __restrict__ v2,
                          u16* __restrict__ hi, u16* __restrict__ lo,
                          float* __restrict__ c2) {
  int w = threadIdx.x >> 6, lane = threadIdx.x & 63;
  int row = blockIdx.x * 4 + w;
  const float4* xr = (const float4*)(x + (size_t)row * DD);
  const float4* vv = (const float4*)v2;
  ushort4* hr = (ushort4*)(hi + (size_t)row * DD);
  ushort4* lr = (ushort4*)(lo + (size_t)row * DD);
  float s = 0.f;
#pragma unroll
  for (int j = 0; j < 4; j++) {
    int idx = j * 64 + lane;
    float4 v = xr[idx];
    float4 b = vv[idx];
    s += v.x * b.x + v.y * b.y + v.z * b.z + v.w * b.w;
    u16 h0 = f2bf(v.x), h1 = f2bf(v.y), h2 = f2bf(v.z), h3 = f2bf(v.w);
    ushort4 hv; hv.x = h0; hv.y = h1; hv.z = h2; hv.w = h3;
    ushort4 lv;
    lv.x = f2bf(v.x - bf2f(h0)); lv.y = f2bf(v.y - bf2f(h1));
    lv.z = f2bf(v.z - bf2f(h2)); lv.w = f2bf(v.w - bf2f(h3));
    hr[idx] = hv;
    lr[idx] = lv;
  }
#pragma unroll
  for (int o = 32; o > 0; o >>= 1) s += __shfl_xor(s, o);
  if (lane == 0) c2[row] = s;
}

// ---- prep: transpose RxC fp32 -> CxR bf16 (hi only) ----------------------
__global__ void k_transpose_split(const float* __restrict__ W, u16* __restrict__ thi,
                                  int R, int C) {
  __shared__ float tile[32][33];
  int c0 = blockIdx.x * 32, r0 = blockIdx.y * 32;
  int tx = threadIdx.x, ty = threadIdx.y;  // block (32,8)
#pragma unroll
  for (int i = 0; i < 4; i++)
    tile[ty + i * 8][tx] = W[(size_t)(r0 + ty + i * 8) * C + c0 + tx];
  __syncthreads();
#pragma unroll
  for (int i = 0; i < 4; i++) {
    float v = tile[tx][ty + i * 8];
    thi[(size_t)(c0 + ty + i * 8) * R + r0 + tx] = f2bf(v);
  }
}

// ---- matvec: out[r] = A[r,:] . v  (wave per row) -------------------------
__global__ void k_matvec(const float* __restrict__ A, const float* __restrict__ v,
                         float* __restrict__ out, int cols) {
  int w = threadIdx.x >> 6, lane = threadIdx.x & 63;
  int row = blockIdx.x * 4 + w;
  const float4* Ar = (const float4*)(A + (size_t)row * cols);
  const float4* vv = (const float4*)v;
  float s = 0.f;
  for (int j = lane; j < cols / 4; j += 64) {
    float4 a = Ar[j], b = vv[j];
    s += a.x * b.x + a.y * b.y + a.z * b.z + a.w * b.w;
  }
#pragma unroll
  for (int o = 32; o > 0; o >>= 1) s += __shfl_xor(s, o);
  if (lane == 0) out[row] = s;
}

// ---- softmax rows of S (+ per-col bias c2) -> P bf16 IN PLACE ------------
__global__ void k_softmax(float* __restrict__ S, const float* __restrict__ c2, int nrows) {
  int w = threadIdx.x >> 6, lane = threadIdx.x & 63;
  int row = blockIdx.x * 4 + w;
  if (row >= nrows) return;
  const float4* Sr = (const float4*)(S + (size_t)row * NN);
  const float4* c2b = (const float4*)(c2 + ((size_t)(row >> 11) << 11));
  float4 v[8];
  float mx = -3.4e38f;
#pragma unroll
  for (int j = 0; j < 8; j++) {
    v[j] = Sr[j * 64 + lane];
    float4 c = c2b[j * 64 + lane];
    v[j].x += c.x; v[j].y += c.y; v[j].z += c.z; v[j].w += c.w;
    mx = fmaxf(mx, fmaxf(fmaxf(v[j].x, v[j].y), fmaxf(v[j].z, v[j].w)));
  }
#pragma unroll
  for (int o = 32; o > 0; o >>= 1) mx = fmaxf(mx, __shfl_xor(mx, o));
  float e[32];
  float sum = 0.f;
#pragma unroll
  for (int j = 0; j < 8; j++) {
    e[j * 4 + 0] = __expf(v[j].x - mx);
    e[j * 4 + 1] = __expf(v[j].y - mx);
    e[j * 4 + 2] = __expf(v[j].z - mx);
    e[j * 4 + 3] = __expf(v[j].w - mx);
    sum += e[j * 4 + 0] + e[j * 4 + 1] + e[j * 4 + 2] + e[j * 4 + 3];
  }
#pragma unroll
  for (int o = 32; o > 0; o >>= 1) sum += __shfl_xor(sum, o);
  float inv = 1.0f / sum;  // depends on every lane's loads -> safe to overwrite row
  ushort4* Pr = (ushort4*)((u16*)S + (size_t)row * PSTRIDE);
#pragma unroll
  for (int j = 0; j < 8; j++) {
    ushort4 pv;
    pv.x = f2bf(e[j * 4 + 0] * inv);
    pv.y = f2bf(e[j * 4 + 1] * inv);
    pv.z = f2bf(e[j * 4 + 2] * inv);
    pv.w = f2bf(e[j * 4 + 3] * inv);
    Pr[j * 64 + lane] = pv;
  }
}

extern "C" void kernel_launch(void* const* d_in, const int* in_sizes, int n_in,
                              void* d_out, int out_size, void* d_ws, size_t ws_size,
                              hipStream_t stream) {
  const float* x = (const float*)d_in[0];
  const float* Wq = (const float*)d_in[1];
  const float* bq = (const float*)d_in[2];
  const float* Wk = (const float*)d_in[3];
  const float* bk = (const float*)d_in[4];
  const float* Wout = (const float*)d_in[5];
  const float* bout = (const float*)d_in[6];
  float* out = (float*)d_out;
  char* ws = (char*)d_ws;

  const size_t MB = 1ull << 20;
  u16* mth = (u16*)(ws + 0 * MB);
  u16* mtl = (u16*)(ws + 2 * MB);
  u16* woutT = (u16*)(ws + 4 * MB);            // 4 MiB [1024][2048]
  float* v2 = (float*)(ws + 8 * MB);           // 4 KiB
  float* c2 = (float*)(ws + 8 * MB + 65536);   // 64 KiB
  char* base = ws + 12 * MB;

  dim3 tb(32, 8, 1);

  if (ws_size >= 204 * MB) {
    // Tier A: xh/xl [0,64), yh/yl [64,128), S/scratch [128,192)
    u16* xh = (u16*)(base);
    u16* xl = (u16*)(base + 32 * MB);
    u16* yh = (u16*)(base + 64 * MB);
    u16* yl = (u16*)(base + 96 * MB);
    char* R = base + 128 * MB;  // 64 MiB scratch: W planes + Mt partials, then S
    u16* wqh = (u16*)(R);
    u16* wql = (u16*)(R + 2 * MB);
    u16* wkh = (u16*)(R + 4 * MB);
    u16* wkl = (u16*)(R + 6 * MB);
    float* mtp = (float*)(R + 8 * MB);  // 16 MiB partials
    float* S = (float*)R;

    // prep
    k_split<<<256, 256, 0, stream>>>(Wq, wqh, wql, (long)DD * DD / 4);
    k_split<<<256, 256, 0, stream>>>(Wk, wkh, wkl, (long)DD * DD / 4);
    k_gemm_mt<<<256, 256, 0, stream>>>(wkh, wkl, wqh, wql, mtp);
    k_combine_split<<<256, 256, 0, stream>>>(mtp, mth, mtl);
    k_transpose_split<<<dim3(32, 64, 1), tb, 0, stream>>>(Wout, woutT, 2048, 1024);
    k_matvec<<<256, 256, 0, stream>>>(Wk, bq, v2, DD);
    k_split_x<<<MT / 4, 256, 0, stream>>>(x, v2, xh, xl, c2);
    // y = x @ Mt^T
    k_gemm_y8<<<256, 512, 0, stream>>>(xh, xl, mth, mtl, yh, yl);
    // per 4-batch half: S, softmax, out
    for (int h = 0; h < 2; h++) {
      size_t qo = (size_t)h * 4 * NN * DD;
      k_gemm_s8<<<256, 512, 0, stream>>>(yh + qo, yl + qo, xh + qo, xl + qo, S);
      k_softmax<<<4 * NN / 4, 256, 0, stream>>>(S, c2 + (size_t)h * 4 * NN, 4 * NN);
      k_gemm_out<<<256, 512, 0, stream>>>((const u16*)S, woutT, bout, out + qo);
    }
  } else if (ws_size >= 156 * MB) {
    // Tier B: xh/xl [0,64), yh/yl [64,128), S 16MB at [128,144)
    u16* xh = (u16*)(base);
    u16* xl = (u16*)(base + 32 * MB);
    u16* yh = (u16*)(base + 64 * MB);
    u16* yl = (u16*)(base + 96 * MB);
    char* R = base + 128 * MB;
    u16* wqh = (u16*)(R);
    u16* wql = (u16*)(R + 2 * MB);
    u16* wkh = (u16*)(R + 4 * MB);
    u16* wkl = (u16*)(R + 6 * MB);
    float* mtp = (float*)yh;  // 16 MiB partials in (not-yet-written) yh region
    float* S = (float*)R;

    k_split<<<256, 256, 0, stream>>>(Wq, wqh, wql, (long)DD * DD / 4);
    k_split<<<256, 256, 0, stream>>>(Wk, wkh, wkl, (long)DD * DD / 4);
    k_gemm_mt<<<256, 256, 0, stream>>>(wkh, wkl, wqh, wql, mtp);
    k_combine_split<<<256, 256, 0, stream>>>(mtp, mth, mtl);
    k_transpose_split<<<dim3(32, 64, 1), tb, 0, stream>>>(Wout, woutT, 2048, 1024);
    k_matvec<<<256, 256, 0, stream>>>(Wk, bq, v2, DD);
    k_split_x<<<MT / 4, 256, 0, stream>>>(x, v2, xh, xl, c2);
    k_gemm_y8<<<256, 512, 0, stream>>>(xh, xl, mth, mtl, yh, yl);
    for (int b = 0; b < BB; b++) {
      size_t qo = (size_t)b * NN * DD;
      k_gemm_s8<<<64, 512, 0, stream>>>(yh + qo, yl + qo, xh + qo, xl + qo, S);
      k_softmax<<<NN / 4, 256, 0, stream>>>(S, c2 + (size_t)b * NN, NN);
      k_gemm_out<<<64, 512, 0, stream>>>((const u16*)S, woutT, bout, out + qo);
    }
  } else {
    // Tier C (60 MiB): per 2-batch chunk, xh/xl 16MB, yh/yl 16MB, S 16MB
    u16* xh = (u16*)(base);
    u16* xl = (u16*)(base + 8 * MB);
    u16* yh = (u16*)(base + 16 * MB);
    u16* yl = (u16*)(base + 24 * MB);
    char* R = base + 32 * MB;
    u16* wqh = (u16*)(R);
    u16* wql = (u16*)(R + 2 * MB);
    u16* wkh = (u16*)(R + 4 * MB);
    u16* wkl = (u16*)(R + 6 * MB);
    float* mtp = (float*)yh;  // 16 MiB partials in yh region (written later)
    float* S = (float*)R;

    k_split<<<256, 256, 0, stream>>>(Wq, wqh, wql, (long)DD * DD / 4);
    k_split<<<256, 256, 0, stream>>>(Wk, wkh, wkl, (long)DD * DD / 4);
    k_gemm_mt<<<256, 256, 0, stream>>>(wkh, wkl, wqh, wql, mtp);
    k_combine_split<<<256, 256, 0, stream>>>(mtp, mth, mtl);
    k_transpose_split<<<dim3(32, 64, 1), tb, 0, stream>>>(Wout, woutT, 2048, 1024);
    k_matvec<<<256, 256, 0, stream>>>(Wk, bq, v2, DD);
    for (int c = 0; c < 4; c++) {
      size_t xo = (size_t)c * 2 * NN * DD;
      k_split_x<<<2 * NN / 4, 256, 0, stream>>>(x + xo, v2, xh, xl, c2 + (size_t)c * 2 * NN);
      k_gemm_y8<<<64, 512, 0, stream>>>(xh, xl, mth, mtl, yh, yl);
      for (int bi = 0; bi < 2; bi++) {
        size_t lo = (size_t)bi * NN * DD;
        k_gemm_s8<<<64, 512, 0, stream>>>(yh + lo, yl + lo, xh + lo, xl + lo, S);
        k_softmax<<<NN / 4, 256, 0, stream>>>(S, c2 + (size_t)(c * 2 + bi) * NN, NN);
        k_gemm_out<<<64, 512, 0, stream>>>((const u16*)S, woutT, bout, out + xo + lo);
      }
    }
  }
}